// Round 4
// baseline (348.888 us; speedup 1.0000x reference)
//
#include <hip/hip_runtime.h>
#include <math.h>

namespace {

typedef __attribute__((ext_vector_type(8))) short  bf16x8;
typedef __attribute__((ext_vector_type(4))) float  f32x4;

constexpr int B_  = 2;
constexpr int H_  = 96;
constexpr int W_  = 96;
constexpr int HW_ = H_ * W_;
constexpr int NC_ = 64;
constexpr int SC_ = 64;

__device__ inline unsigned short f2bf(float f) {
    union { float f; unsigned u; } v; v.f = f;
    unsigned r = v.u + 0x7FFFu + ((v.u >> 16) & 1u);
    return (unsigned short)(r >> 16);
}

__device__ inline bf16x8 ld_frag_g(const unsigned short* p) {   // global, 16B aligned
    return *reinterpret_cast<const bf16x8*>(p);
}
__device__ inline bf16x8 ld_frag_s(const unsigned short* p) {   // LDS, 16B aligned
    return *reinterpret_cast<const bf16x8*>(p);
}

// ---------------------------------------------------------------------------
// prep: cast weights to bf16 in MFMA-friendly layouts.
//  wb1  [16][1152]  k = ic*9+tap (flat cast of w1)
//  wb2  [64][160]   k<144 real (flat), else 0
//  wboff[32][576]   rows 0..26 real, 27..31 zero
//  wbg  [64][576], wbbe[64][576]  flat casts
//  wbd  [64][576]   k' = tap*64+ic  (matches dcn gather layout)
// ---------------------------------------------------------------------------
__global__ __launch_bounds__(256)
void prep_weights(const float* __restrict__ w1, const float* __restrict__ w2,
                  const float* __restrict__ woff, const float* __restrict__ wg,
                  const float* __restrict__ wbe, const float* __restrict__ wdcn,
                  unsigned short* __restrict__ wb1, unsigned short* __restrict__ wb2,
                  unsigned short* __restrict__ wboff, unsigned short* __restrict__ wbg,
                  unsigned short* __restrict__ wbbe, unsigned short* __restrict__ wbd) {
    int idx = blockIdx.x * 256 + threadIdx.x;
    if (idx < 16 * 1152) wb1[idx] = f2bf(w1[idx]);
    if (idx < 64 * 160) {
        int oc = idx / 160, k = idx - oc * 160;
        wb2[idx] = (k < 144) ? f2bf(w2[oc * 144 + k]) : (unsigned short)0;
    }
    if (idx < 32 * 576) {
        int oc = idx / 576, k = idx - oc * 576;
        wboff[idx] = (oc < 27) ? f2bf(woff[oc * 576 + k]) : (unsigned short)0;
    }
    if (idx < 64 * 576) {
        wbg[idx]  = f2bf(wg[idx]);
        wbbe[idx] = f2bf(wbe[idx]);
        int oc = idx / 576, r = idx - oc * 576;
        int tap = r >> 6, ic = r & 63;
        wbd[idx] = f2bf(wdcn[oc * 576 + ic * 9 + tap]);
    }
}

// ---------------------------------------------------------------------------
// positional_norm (unchanged)
// ---------------------------------------------------------------------------
__global__ __launch_bounds__(256)
void norm_kernel(const float* __restrict__ x, float* __restrict__ nrm) {
    __shared__ float red1[4][64];
    __shared__ float red2[4][64];
    int blk = blockIdx.x;
    int b   = blk / 144;
    int p   = (blk % 144) * 64 + (threadIdx.x & 63);
    int cg  = threadIdx.x >> 6;

    float v[16];
    float s1 = 0.f, s2 = 0.f;
    const float* xb = x + ((size_t)b * NC_ + cg * 16) * HW_ + p;
    #pragma unroll
    for (int j = 0; j < 16; ++j) {
        v[j] = xb[j * HW_];
        s1 += v[j];
        s2 = fmaf(v[j], v[j], s2);
    }
    red1[cg][threadIdx.x & 63] = s1;
    red2[cg][threadIdx.x & 63] = s2;
    __syncthreads();
    int px = threadIdx.x & 63;
    s1 = red1[0][px] + red1[1][px] + red1[2][px] + red1[3][px];
    s2 = red2[0][px] + red2[1][px] + red2[2][px] + red2[3][px];
    float mean = s1 * (1.f / 64.f);
    float var  = (s2 - 64.f * mean * mean) * (1.f / 63.f);
    float inv  = 1.f / sqrtf(var + 1e-5f);
    float* nb = nrm + ((size_t)b * NC_ + cg * 16) * HW_ + p;
    #pragma unroll
    for (int j = 0; j < 16; ++j)
        nb[j * HW_] = (v[j] - mean) * inv;
}

// ---------------------------------------------------------------------------
// MFMA implicit-GEMM 3x3 conv, pad 1.  Block = 64 px (16w x 4h), 256 thr.
// P (im2col, bf16) built in LDS per K-chunk; W frags read from global (L2).
// mfma(W_frag, P_frag, acc): D row (fq*4+j) = oc, D col (fr) = px.
// Wave split: NOCT = COUT_PAD/16 oc-tiles; WPO = 4/NOCT waves per oc-tile;
// each wave does MTP = NOCT m-tiles. DUAL: gamma/beta two W sets + epilogue.
// ---------------------------------------------------------------------------
template <int CIN1, int CIN2, int NCH, int KC, int ROWP, int COUT_PAD,
          int COUT_REAL, int KREAL, bool DUAL, bool RELU>
__global__ __launch_bounds__(256)
void conv_mfma(const float* __restrict__ in1, const float* __restrict__ in2,
               const unsigned short* __restrict__ Wb,
               const unsigned short* __restrict__ Wb2,
               const float* __restrict__ bias, const float* __restrict__ bias2,
               const float* __restrict__ nrm, float* __restrict__ out) {
    constexpr int NOCT = COUT_PAD / 16;
    constexpr int WPO  = 4 / NOCT;
    constexpr int MTP  = NOCT;
    constexpr int NACC = DUAL ? 2 : 1;
    constexpr int KTOT = NCH * KC;

    __shared__ unsigned short P[64 * ROWP];

    int t   = threadIdx.x;
    int blk = blockIdx.x;                 // 288 = B * 24 * 6
    int bx  = blk % 6;
    int by  = (blk / 6) % 24;
    int b   = blk / 144;
    int x0  = bx * 16, y0 = by * 4;

    int wave = t >> 6, lane = t & 63;
    int fr = lane & 15, fq = lane >> 4;
    int oct  = wave / WPO;
    int widx = wave - oct * WPO;
    int mt0  = widx * MTP;

    f32x4 acc[MTP][NACC];
    #pragma unroll
    for (int i = 0; i < MTP; ++i)
        #pragma unroll
        for (int a = 0; a < NACC; ++a)
            acc[i][a] = (f32x4){0.f, 0.f, 0.f, 0.f};

    for (int ch = 0; ch < NCH; ++ch) {
        // ---- build P chunk (bf16 im2col) ----
        for (int e = t; e < 64 * KC; e += 256) {
            int m  = e & 63;
            int kk = e >> 6;
            int k  = ch * KC + kk;
            float val = 0.f;
            if (k < KREAL) {
                int ic  = k / 9;
                int tap = k - ic * 9;
                int dy  = tap / 3;
                int dx  = tap - dy * 3;
                int yy = y0 + (m >> 4) + dy - 1;
                int xx = x0 + (m & 15) + dx - 1;
                if ((unsigned)yy < (unsigned)H_ && (unsigned)xx < (unsigned)W_) {
                    const float* s = (CIN2 == 0 || ic < CIN1)
                        ? in1 + ((size_t)b * CIN1 + ic) * HW_
                        : in2 + ((size_t)b * CIN2 + (ic - CIN1)) * HW_;
                    val = s[yy * W_ + xx];
                }
            }
            P[m * ROWP + kk] = f2bf(val);
        }
        __syncthreads();

        // ---- MFMA over this chunk ----
        for (int ks = 0; ks < KC / 32; ++ks) {
            int ko = ch * KC + ks * 32 + fq * 8;
            bf16x8 wfA = ld_frag_g(&Wb[(size_t)(oct * 16 + fr) * KTOT + ko]);
            bf16x8 wfB;
            if (DUAL) wfB = ld_frag_g(&Wb2[(size_t)(oct * 16 + fr) * KTOT + ko]);
            #pragma unroll
            for (int i = 0; i < MTP; ++i) {
                bf16x8 pf = ld_frag_s(&P[(size_t)((mt0 + i) * 16 + fr) * ROWP + ks * 32 + fq * 8]);
                acc[i][0] = __builtin_amdgcn_mfma_f32_16x16x32_bf16(wfA, pf, acc[i][0], 0, 0, 0);
                if (DUAL)
                    acc[i][1] = __builtin_amdgcn_mfma_f32_16x16x32_bf16(wfB, pf, acc[i][1], 0, 0, 0);
            }
        }
        __syncthreads();
    }

    // ---- store ----
    #pragma unroll
    for (int i = 0; i < MTP; ++i) {
        int py = mt0 + i;                 // m-tile == tile row
        #pragma unroll
        for (int j = 0; j < 4; ++j) {
            int oc = oct * 16 + fq * 4 + j;
            if (oc >= COUT_REAL) continue;
            size_t off = ((size_t)b * COUT_REAL + oc) * HW_ + (size_t)(y0 + py) * W_ + x0 + fr;
            float v = acc[i][0][j] + bias[oc];
            if (DUAL) {
                float be = acc[i][1][j] + bias2[oc];
                float nv = nrm[off];
                out[off] = fmaf(nv, 1.f + v, be);
            } else {
                out[off] = RELU ? fmaxf(v, 0.f) : v;
            }
        }
    }
}

// ---------------------------------------------------------------------------
// DCNv2 fused. Block = 16 px, 256 thr.
// phase0: 144 thr -> mask-folded corner weights/indices (LDS)
// phase1: gather, bf16 write s[pp][k*64+c] (k-major, matches wbd)
// phase2: wave w = oc-tile w; 18 k-steps x (1 W global b128 + 1 P ds b128 + mfma)
// ---------------------------------------------------------------------------
constexpr int SROW = 584;                 // u16 units; 584/8 = 73 (odd -> no conflict)

__global__ __launch_bounds__(256)
void dcn_kernel(const float* __restrict__ ref, const float* __restrict__ om,
                const unsigned short* __restrict__ wbd, const float* __restrict__ b_dcn,
                float* __restrict__ out) {
    __shared__ unsigned short sS[16 * SROW];   // 18.25 KiB
    __shared__ float4 cwL[144];
    __shared__ int4   ciL[144];

    int t  = threadIdx.x;
    int b  = blockIdx.x / 576;
    int p0 = (blockIdx.x % 576) * 16;

    const float* refb = ref + (size_t)b * SC_ * HW_;
    const float* omb  = om  + (size_t)b * 27  * HW_;

    // ---- phase 0 ----
    if (t < 144) {
        int pp = t / 9, k = t - pp * 9;
        int p  = p0 + pp;
        int y  = p / W_, x = p - y * W_;
        float dy = omb[(2 * k)     * HW_ + p];
        float dx = omb[(2 * k + 1) * HW_ + p];
        float mk = omb[(18 + k)    * HW_ + p];
        mk = 1.f / (1.f + expf(-mk));

        float py = dy + (float)y + (float)(k / 3 - 1);
        float px = dx + (float)x + (float)(k % 3 - 1);
        float fy = floorf(py), fx = floorf(px);
        int   y0 = (int)fy,   x0 = (int)fx;
        float wy = py - fy,   wx = px - fx;

        float cw[4];
        int   ci[4];
        #pragma unroll
        for (int i = 0; i < 4; ++i) {
            int yy = y0 + (i >> 1);
            int xx = x0 + (i & 1);
            bool valid = (yy >= 0) && (yy < H_) && (xx >= 0) && (xx < W_);
            int yc = yy < 0 ? 0 : (yy > H_ - 1 ? H_ - 1 : yy);
            int xc = xx < 0 ? 0 : (xx > W_ - 1 ? W_ - 1 : xx);
            ci[i] = yc * W_ + xc;
            float wyi = (i >> 1) ? wy : (1.f - wy);
            float wxi = (i & 1)  ? wx : (1.f - wx);
            cw[i] = valid ? mk * wyi * wxi : 0.f;
        }
        cwL[t] = make_float4(cw[0], cw[1], cw[2], cw[3]);
        ciL[t] = make_int4(ci[0], ci[1], ci[2], ci[3]);
    }
    __syncthreads();

    // ---- phase 1: gather (bf16) ----
    {
        int pp = t >> 4, sub = t & 15;
        #pragma unroll
        for (int k = 0; k < 9; ++k) {
            float4 cw = cwL[pp * 9 + k];
            int4   ci = ciL[pp * 9 + k];
            ushort4 sv;
            {
                const float* rc = refb + (size_t)(sub * 4 + 0) * HW_;
                sv.x = f2bf(cw.x * rc[ci.x] + cw.y * rc[ci.y] + cw.z * rc[ci.z] + cw.w * rc[ci.w]);
            }
            {
                const float* rc = refb + (size_t)(sub * 4 + 1) * HW_;
                sv.y = f2bf(cw.x * rc[ci.x] + cw.y * rc[ci.y] + cw.z * rc[ci.z] + cw.w * rc[ci.w]);
            }
            {
                const float* rc = refb + (size_t)(sub * 4 + 2) * HW_;
                sv.z = f2bf(cw.x * rc[ci.x] + cw.y * rc[ci.y] + cw.z * rc[ci.z] + cw.w * rc[ci.w]);
            }
            {
                const float* rc = refb + (size_t)(sub * 4 + 3) * HW_;
                sv.w = f2bf(cw.x * rc[ci.x] + cw.y * rc[ci.y] + cw.z * rc[ci.z] + cw.w * rc[ci.w]);
            }
            *reinterpret_cast<ushort4*>(&sS[pp * SROW + k * 64 + sub * 4]) = sv;
        }
    }
    __syncthreads();

    // ---- phase 2: MFMA matvec ----
    int wave = t >> 6, lane = t & 63;
    int fr = lane & 15, fq = lane >> 4;

    f32x4 acc = (f32x4){0.f, 0.f, 0.f, 0.f};
    for (int ks = 0; ks < 18; ++ks) {
        bf16x8 wf = ld_frag_g(&wbd[(size_t)(wave * 16 + fr) * 576 + ks * 32 + fq * 8]);
        bf16x8 pf = ld_frag_s(&sS[(size_t)fr * SROW + ks * 32 + fq * 8]);
        acc = __builtin_amdgcn_mfma_f32_16x16x32_bf16(wf, pf, acc, 0, 0, 0);
    }

    float* outb = out + (size_t)b * SC_ * HW_;
    #pragma unroll
    for (int j = 0; j < 4; ++j) {
        int oc = wave * 16 + fq * 4 + j;
        outb[(size_t)oc * HW_ + p0 + fr] = acc[j] + b_dcn[oc];
    }
}

} // namespace

// ---------------------------------------------------------------------------
extern "C" void kernel_launch(void* const* d_in, const int* in_sizes, int n_in,
                              void* d_out, int out_size, void* d_ws, size_t ws_size,
                              hipStream_t stream) {
    (void)in_sizes; (void)n_in; (void)out_size; (void)ws_size;

    const float* x     = (const float*)d_in[0];
    const float* ref   = (const float*)d_in[1];
    const float* w1    = (const float*)d_in[2];
    const float* b1    = (const float*)d_in[3];
    const float* w2    = (const float*)d_in[4];
    const float* b2    = (const float*)d_in[5];
    const float* w_off = (const float*)d_in[6];
    const float* b_off = (const float*)d_in[7];
    const float* w_dcn = (const float*)d_in[8];
    const float* b_dcn = (const float*)d_in[9];
    const float* w_g   = (const float*)d_in[10];
    const float* b_g   = (const float*)d_in[11];
    const float* w_be  = (const float*)d_in[12];
    const float* b_be  = (const float*)d_in[13];

    float* out = (float*)d_out;
    float* ws  = (float*)d_ws;

    float* nrm   = ws;                      // 1,179,648 f
    float* hmid  = nrm   + 1179648;         //   294,912 f
    float* cond  = hmid  + 294912;          // 1,179,648 f
    float* om    = cond  + 1179648;         //   497,664 f
    float* rr    = om    + 497664;          // 1,179,648 f
    unsigned short* wb1   = (unsigned short*)(rr + 1179648);  // 18,432 u16
    unsigned short* wb2   = wb1   + 18432;                    // 10,240
    unsigned short* wboff = wb2   + 10240;                    // 18,432
    unsigned short* wbg   = wboff + 18432;                    // 36,864
    unsigned short* wbbe  = wbg   + 36864;                    // 36,864
    unsigned short* wbd   = wbbe  + 36864;                    // 36,864

    prep_weights<<<144, 256, 0, stream>>>(w1, w2, w_off, w_g, w_be, w_dcn,
                                          wb1, wb2, wboff, wbg, wbbe, wbd);

    norm_kernel<<<288, 256, 0, stream>>>(x, nrm);

    constexpr int GRID = 288;

    // conv1: 128 -> 16, ReLU. 4 chunks of 32 ch (K=288 each), KREAL=1152.
    conv_mfma<64, 64, 4, 288, 296, 16, 16, 1152, false, true>
        <<<GRID, 256, 0, stream>>>(nrm, ref, wb1, nullptr, b1, nullptr, nullptr, hmid);

    // conv2: 16 -> 64, ReLU. 1 chunk K=160 (144 real).
    conv_mfma<16, 0, 1, 160, 168, 64, 64, 144, false, true>
        <<<GRID, 256, 0, stream>>>(hmid, nullptr, wb2, nullptr, b2, nullptr, nullptr, cond);

    // conv_off: 64 -> 27 (pad 32). 2 chunks K=288.
    conv_mfma<64, 0, 2, 288, 296, 32, 27, 576, false, false>
        <<<GRID, 256, 0, stream>>>(cond, nullptr, wboff, nullptr, b_off, nullptr, nullptr, om);

    dcn_kernel<<<B_ * 576, 256, 0, stream>>>(ref, om, wbd, b_dcn, rr);

    // final: gamma/beta DUAL + fused affine epilogue. 2 chunks K=288.
    conv_mfma<64, 0, 2, 288, 296, 64, 64, 576, true, false>
        <<<GRID, 256, 0, stream>>>(rr, nullptr, wbg, wbbe, b_g, b_be, nrm, out);
}

// Round 5
// 191.941 us; speedup vs baseline: 1.8177x; 1.8177x over previous
//
#include <hip/hip_runtime.h>
#include <math.h>

namespace {

typedef __attribute__((ext_vector_type(8))) short  bf16x8;
typedef __attribute__((ext_vector_type(4))) float  f32x4;

constexpr int B_  = 2;
constexpr int H_  = 96;
constexpr int W_  = 96;
constexpr int HW_ = H_ * W_;
constexpr int NC_ = 64;
constexpr int SC_ = 64;

__device__ inline unsigned short f2bf(float f) {
    union { float f; unsigned u; } v; v.f = f;
    unsigned r = v.u + 0x7FFFu + ((v.u >> 16) & 1u);
    return (unsigned short)(r >> 16);
}

__device__ inline bf16x8 ld_frag(const unsigned short* p) {
    return *reinterpret_cast<const bf16x8*>(p);
}

// ---------------------------------------------------------------------------
// prep: weights -> bf16, tap-major [tap][ocp][icp] (A-frag friendly).
//  wt1  [9][16][128]          wt2   [9][64][32]  (ic>=16 zero)
//  wtoff[9][32][64] (oc>=27=0) wtg/wtbe [9][64][64]
//  wbd  [64][576]  k' = tap*64+ic (dcn gather layout)
// ---------------------------------------------------------------------------
__global__ __launch_bounds__(256)
void prep_weights(const float* __restrict__ w1, const float* __restrict__ w2,
                  const float* __restrict__ woff, const float* __restrict__ wg,
                  const float* __restrict__ wbe, const float* __restrict__ wdcn,
                  unsigned short* __restrict__ wt1, unsigned short* __restrict__ wt2,
                  unsigned short* __restrict__ wtoff, unsigned short* __restrict__ wtg,
                  unsigned short* __restrict__ wtbe, unsigned short* __restrict__ wbd) {
    int idx = blockIdx.x * 256 + threadIdx.x;
    if (idx < 9 * 16 * 128) {
        int tap = idx / (16 * 128), oc = (idx / 128) % 16, ic = idx % 128;
        wt1[idx] = f2bf(w1[(oc * 128 + ic) * 9 + tap]);
    }
    if (idx < 9 * 64 * 32) {
        int tap = idx / (64 * 32), oc = (idx / 32) % 64, ic = idx % 32;
        wt2[idx] = (ic < 16) ? f2bf(w2[(oc * 16 + ic) * 9 + tap]) : (unsigned short)0;
    }
    if (idx < 9 * 32 * 64) {
        int tap = idx / (32 * 64), oc = (idx / 64) % 32, ic = idx % 64;
        wtoff[idx] = (oc < 27) ? f2bf(woff[(oc * 64 + ic) * 9 + tap]) : (unsigned short)0;
    }
    if (idx < 9 * 64 * 64) {
        int tap = idx / (64 * 64), oc = (idx / 64) % 64, ic = idx % 64;
        wtg[idx]  = f2bf(wg [(oc * 64 + ic) * 9 + tap]);
        wtbe[idx] = f2bf(wbe[(oc * 64 + ic) * 9 + tap]);
    }
    if (idx < 64 * 576) {
        int oc = idx / 576, r = idx - oc * 576;
        int tap = r >> 6, ic = r & 63;
        wbd[idx] = f2bf(wdcn[oc * 576 + ic * 9 + tap]);
    }
}

// ---------------------------------------------------------------------------
// positional_norm (unchanged)
// ---------------------------------------------------------------------------
__global__ __launch_bounds__(256)
void norm_kernel(const float* __restrict__ x, float* __restrict__ nrm) {
    __shared__ float red1[4][64];
    __shared__ float red2[4][64];
    int blk = blockIdx.x;
    int b   = blk / 144;
    int p   = (blk % 144) * 64 + (threadIdx.x & 63);
    int cg  = threadIdx.x >> 6;

    float v[16];
    float s1 = 0.f, s2 = 0.f;
    const float* xb = x + ((size_t)b * NC_ + cg * 16) * HW_ + p;
    #pragma unroll
    for (int j = 0; j < 16; ++j) {
        v[j] = xb[j * HW_];
        s1 += v[j];
        s2 = fmaf(v[j], v[j], s2);
    }
    red1[cg][threadIdx.x & 63] = s1;
    red2[cg][threadIdx.x & 63] = s2;
    __syncthreads();
    int px = threadIdx.x & 63;
    s1 = red1[0][px] + red1[1][px] + red1[2][px] + red1[3][px];
    s2 = red2[0][px] + red2[1][px] + red2[2][px] + red2[3][px];
    float mean = s1 * (1.f / 64.f);
    float var  = (s2 - 64.f * mean * mean) * (1.f / 63.f);
    float inv  = 1.f / sqrtf(var + 1e-5f);
    float* nb = nrm + ((size_t)b * NC_ + cg * 16) * HW_ + p;
    #pragma unroll
    for (int j = 0; j < 16; ++j)
        nb[j * HW_] = (v[j] - mean) * inv;
}

// ---------------------------------------------------------------------------
// Tap-decomposed MFMA conv 3x3, pad 1.  Block = 64 px (16w x 4h), 256 thr.
// Stage patch ONCE: patch[row 0..5][col 0..17][ic 0..ICP) bf16, stride COLP.
// Per tap (dy,dx): B-frag = ds_read_b128 at pixel (mt+dy, fr+dx), k=ic.
// A-frag = 16B global load from wt[tap][oct*16+fr][k]. 9 taps x ICP/32 ksteps.
// Wave split: oct = wave/WPO, m-tiles mt0..mt0+MTP-1.
// ---------------------------------------------------------------------------
template <int CIN1, int CIN2, int ICP, int COLP, int COUT_PAD, int COUT_REAL,
          bool DUAL, bool RELU>
__global__ __launch_bounds__(256)
void conv_tap(const float* __restrict__ in1, const float* __restrict__ in2,
              const unsigned short* __restrict__ Wt,
              const unsigned short* __restrict__ Wt2,
              const float* __restrict__ bias, const float* __restrict__ bias2,
              const float* __restrict__ nrm, float* __restrict__ out) {
    constexpr int CIN  = CIN1 + CIN2;
    constexpr int NOCT = COUT_PAD / 16;
    constexpr int WPO  = 4 / NOCT;
    constexpr int MTP  = NOCT;            // = 4 / WPO
    constexpr int NACC = DUAL ? 2 : 1;
    constexpr int NKS  = ICP / 32;

    __shared__ unsigned short patch[6 * 18 * COLP];

    int t   = threadIdx.x;
    int blk = blockIdx.x;                 // 288 = B * 24 * 6
    int bx  = blk % 6;
    int by  = (blk / 6) % 24;
    int b   = blk / 144;
    int x0  = bx * 16, y0 = by * 4;

    // ---- stage patch (once) ----
    constexpr int NST = 6 * ICP * 18;
    for (int e = t; e < NST; e += 256) {
        int col = e % 18;
        int rem = e / 18;
        int ic  = rem % ICP;
        int row = rem / ICP;
        int yy = y0 + row - 1, xx = x0 + col - 1;
        float val = 0.f;
        if (ic < CIN && (unsigned)yy < (unsigned)H_ && (unsigned)xx < (unsigned)W_) {
            const float* src = (CIN2 == 0 || ic < CIN1)
                ? in1 + ((size_t)b * CIN1 + ic) * HW_
                : in2 + ((size_t)b * CIN2 + (ic - CIN1)) * HW_;
            val = src[yy * W_ + xx];
        }
        patch[(row * 18 + col) * COLP + ic] = f2bf(val);
    }
    __syncthreads();

    // ---- MFMA: 9 taps x NKS k-steps x MTP m-tiles ----
    int wave = t >> 6, lane = t & 63;
    int fr = lane & 15, fq = lane >> 4;
    int oct  = wave / WPO;
    int widx = wave - oct * WPO;
    int mt0  = widx * MTP;

    f32x4 acc[MTP][NACC];
    #pragma unroll
    for (int i = 0; i < MTP; ++i)
        #pragma unroll
        for (int a = 0; a < NACC; ++a)
            acc[i][a] = (f32x4){0.f, 0.f, 0.f, 0.f};

    constexpr int dyv[9] = {0,0,0,1,1,1,2,2,2};
    constexpr int dxv[9] = {0,1,2,0,1,2,0,1,2};

    #pragma unroll
    for (int tap = 0; tap < 9; ++tap) {
        int dy = dyv[tap], dx = dxv[tap];
        #pragma unroll
        for (int ks = 0; ks < NKS; ++ks) {
            const size_t wo = ((size_t)tap * COUT_PAD + oct * 16 + fr) * ICP + ks * 32 + fq * 8;
            bf16x8 wfA = ld_frag(&Wt[wo]);
            bf16x8 wfB;
            if (DUAL) wfB = ld_frag(&Wt2[wo]);
            #pragma unroll
            for (int i = 0; i < MTP; ++i) {
                bf16x8 pf = ld_frag(&patch[((mt0 + i + dy) * 18 + (fr + dx)) * COLP
                                           + ks * 32 + fq * 8]);
                acc[i][0] = __builtin_amdgcn_mfma_f32_16x16x32_bf16(wfA, pf, acc[i][0], 0, 0, 0);
                if (DUAL)
                    acc[i][1] = __builtin_amdgcn_mfma_f32_16x16x32_bf16(wfB, pf, acc[i][1], 0, 0, 0);
            }
        }
    }

    // ---- store ----
    #pragma unroll
    for (int i = 0; i < MTP; ++i) {
        int py = mt0 + i;
        #pragma unroll
        for (int j = 0; j < 4; ++j) {
            int oc = oct * 16 + fq * 4 + j;
            if (oc >= COUT_REAL) continue;
            size_t off = ((size_t)b * COUT_REAL + oc) * HW_ + (size_t)(y0 + py) * W_ + x0 + fr;
            float v = acc[i][0][j] + bias[oc];
            if (DUAL) {
                float be = acc[i][1][j] + bias2[oc];
                float nv = nrm[off];
                out[off] = fmaf(nv, 1.f + v, be);
            } else {
                out[off] = RELU ? fmaxf(v, 0.f) : v;
            }
        }
    }
}

// ---------------------------------------------------------------------------
// DCNv2 fused (round-4 version, validated). Block = 16 px, 256 thr.
// ---------------------------------------------------------------------------
constexpr int SROW = 584;

__global__ __launch_bounds__(256)
void dcn_kernel(const float* __restrict__ ref, const float* __restrict__ om,
                const unsigned short* __restrict__ wbd, const float* __restrict__ b_dcn,
                float* __restrict__ out) {
    __shared__ unsigned short sS[16 * SROW];
    __shared__ float4 cwL[144];
    __shared__ int4   ciL[144];

    int t  = threadIdx.x;
    int b  = blockIdx.x / 576;
    int p0 = (blockIdx.x % 576) * 16;

    const float* refb = ref + (size_t)b * SC_ * HW_;
    const float* omb  = om  + (size_t)b * 27  * HW_;

    if (t < 144) {
        int pp = t / 9, k = t - pp * 9;
        int p  = p0 + pp;
        int y  = p / W_, x = p - y * W_;
        float dy = omb[(2 * k)     * HW_ + p];
        float dx = omb[(2 * k + 1) * HW_ + p];
        float mk = omb[(18 + k)    * HW_ + p];
        mk = 1.f / (1.f + expf(-mk));

        float py = dy + (float)y + (float)(k / 3 - 1);
        float px = dx + (float)x + (float)(k % 3 - 1);
        float fy = floorf(py), fx = floorf(px);
        int   y0 = (int)fy,   x0 = (int)fx;
        float wy = py - fy,   wx = px - fx;

        float cw[4];
        int   ci[4];
        #pragma unroll
        for (int i = 0; i < 4; ++i) {
            int yy = y0 + (i >> 1);
            int xx = x0 + (i & 1);
            bool valid = (yy >= 0) && (yy < H_) && (xx >= 0) && (xx < W_);
            int yc = yy < 0 ? 0 : (yy > H_ - 1 ? H_ - 1 : yy);
            int xc = xx < 0 ? 0 : (xx > W_ - 1 ? W_ - 1 : xx);
            ci[i] = yc * W_ + xc;
            float wyi = (i >> 1) ? wy : (1.f - wy);
            float wxi = (i & 1)  ? wx : (1.f - wx);
            cw[i] = valid ? mk * wyi * wxi : 0.f;
        }
        cwL[t] = make_float4(cw[0], cw[1], cw[2], cw[3]);
        ciL[t] = make_int4(ci[0], ci[1], ci[2], ci[3]);
    }
    __syncthreads();

    {
        int pp = t >> 4, sub = t & 15;
        #pragma unroll
        for (int k = 0; k < 9; ++k) {
            float4 cw = cwL[pp * 9 + k];
            int4   ci = ciL[pp * 9 + k];
            ushort4 sv;
            {
                const float* rc = refb + (size_t)(sub * 4 + 0) * HW_;
                sv.x = f2bf(cw.x * rc[ci.x] + cw.y * rc[ci.y] + cw.z * rc[ci.z] + cw.w * rc[ci.w]);
            }
            {
                const float* rc = refb + (size_t)(sub * 4 + 1) * HW_;
                sv.y = f2bf(cw.x * rc[ci.x] + cw.y * rc[ci.y] + cw.z * rc[ci.z] + cw.w * rc[ci.w]);
            }
            {
                const float* rc = refb + (size_t)(sub * 4 + 2) * HW_;
                sv.z = f2bf(cw.x * rc[ci.x] + cw.y * rc[ci.y] + cw.z * rc[ci.z] + cw.w * rc[ci.w]);
            }
            {
                const float* rc = refb + (size_t)(sub * 4 + 3) * HW_;
                sv.w = f2bf(cw.x * rc[ci.x] + cw.y * rc[ci.y] + cw.z * rc[ci.z] + cw.w * rc[ci.w]);
            }
            *reinterpret_cast<ushort4*>(&sS[pp * SROW + k * 64 + sub * 4]) = sv;
        }
    }
    __syncthreads();

    int wave = t >> 6, lane = t & 63;
    int fr = lane & 15, fq = lane >> 4;

    f32x4 acc = (f32x4){0.f, 0.f, 0.f, 0.f};
    for (int ks = 0; ks < 18; ++ks) {
        bf16x8 wf = ld_frag(&wbd[(size_t)(wave * 16 + fr) * 576 + ks * 32 + fq * 8]);
        bf16x8 pf = ld_frag(&sS[(size_t)fr * SROW + ks * 32 + fq * 8]);
        acc = __builtin_amdgcn_mfma_f32_16x16x32_bf16(wf, pf, acc, 0, 0, 0);
    }

    float* outb = out + (size_t)b * SC_ * HW_;
    #pragma unroll
    for (int j = 0; j < 4; ++j) {
        int oc = wave * 16 + fq * 4 + j;
        outb[(size_t)oc * HW_ + p0 + fr] = acc[j] + b_dcn[oc];
    }
}

} // namespace

// ---------------------------------------------------------------------------
extern "C" void kernel_launch(void* const* d_in, const int* in_sizes, int n_in,
                              void* d_out, int out_size, void* d_ws, size_t ws_size,
                              hipStream_t stream) {
    (void)in_sizes; (void)n_in; (void)out_size; (void)ws_size;

    const float* x     = (const float*)d_in[0];
    const float* ref   = (const float*)d_in[1];
    const float* w1    = (const float*)d_in[2];
    const float* b1    = (const float*)d_in[3];
    const float* w2    = (const float*)d_in[4];
    const float* b2    = (const float*)d_in[5];
    const float* w_off = (const float*)d_in[6];
    const float* b_off = (const float*)d_in[7];
    const float* w_dcn = (const float*)d_in[8];
    const float* b_dcn = (const float*)d_in[9];
    const float* w_g   = (const float*)d_in[10];
    const float* b_g   = (const float*)d_in[11];
    const float* w_be  = (const float*)d_in[12];
    const float* b_be  = (const float*)d_in[13];

    float* out = (float*)d_out;
    float* ws  = (float*)d_ws;

    float* nrm   = ws;                      // 1,179,648 f
    float* hmid  = nrm   + 1179648;         //   294,912 f
    float* cond  = hmid  + 294912;          // 1,179,648 f
    float* om    = cond  + 1179648;         //   497,664 f
    float* rr    = om    + 497664;          // 1,179,648 f
    unsigned short* wt1   = (unsigned short*)(rr + 1179648);  // 18,432
    unsigned short* wt2   = wt1   + 18432;                    // 18,432
    unsigned short* wtoff = wt2   + 18432;                    // 18,432
    unsigned short* wtg   = wtoff + 18432;                    // 36,864
    unsigned short* wtbe  = wtg   + 36864;                    // 36,864
    unsigned short* wbd   = wtbe  + 36864;                    // 36,864

    prep_weights<<<144, 256, 0, stream>>>(w1, w2, w_off, w_g, w_be, w_dcn,
                                          wt1, wt2, wtoff, wtg, wtbe, wbd);

    norm_kernel<<<288, 256, 0, stream>>>(x, nrm);

    constexpr int GRID = 288;

    // conv1: 128 -> 16, ReLU. ICP=128, COLP=136.
    conv_tap<64, 64, 128, 136, 16, 16, false, true>
        <<<GRID, 256, 0, stream>>>(nrm, ref, wt1, nullptr, b1, nullptr, nullptr, hmid);

    // conv2: 16 -> 64, ReLU. ICP=32, COLP=40.
    conv_tap<16, 0, 32, 40, 64, 64, false, true>
        <<<GRID, 256, 0, stream>>>(hmid, nullptr, wt2, nullptr, b2, nullptr, nullptr, cond);

    // conv_off: 64 -> 27 (pad 32). ICP=64, COLP=72.
    conv_tap<64, 0, 64, 72, 32, 27, false, false>
        <<<GRID, 256, 0, stream>>>(cond, nullptr, wtoff, nullptr, b_off, nullptr, nullptr, om);

    dcn_kernel<<<B_ * 576, 256, 0, stream>>>(ref, om, wbd, b_dcn, rr);

    // final: gamma/beta DUAL + fused affine epilogue. ICP=64, COLP=72.
    conv_tap<64, 0, 64, 72, 64, 64, true, false>
        <<<GRID, 256, 0, stream>>>(rr, nullptr, wtg, wtbe, b_g, b_be, nrm, out);
}

// Round 6
// 124.333 us; speedup vs baseline: 2.8061x; 1.5438x over previous
//
#include <hip/hip_runtime.h>
#include <math.h>

namespace {

typedef __attribute__((ext_vector_type(8))) short  bf16x8;
typedef __attribute__((ext_vector_type(4))) float  f32x4;

constexpr int B_  = 2;
constexpr int H_  = 96;
constexpr int W_  = 96;
constexpr int HW_ = H_ * W_;
constexpr int NC_ = 64;
constexpr int SC_ = 64;

__device__ inline unsigned short f2bf(float f) {
    union { float f; unsigned u; } v; v.f = f;
    unsigned r = v.u + 0x7FFFu + ((v.u >> 16) & 1u);
    return (unsigned short)(r >> 16);
}

__device__ inline bf16x8 ld_frag(const unsigned short* p) {
    return *reinterpret_cast<const bf16x8*>(p);
}

// ---------------------------------------------------------------------------
// prep: weights -> bf16, tap-major [tap][ocp][icp] (A-frag friendly).
// ---------------------------------------------------------------------------
__global__ __launch_bounds__(256)
void prep_weights(const float* __restrict__ w1, const float* __restrict__ w2,
                  const float* __restrict__ woff, const float* __restrict__ wg,
                  const float* __restrict__ wbe, const float* __restrict__ wdcn,
                  unsigned short* __restrict__ wt1, unsigned short* __restrict__ wt2,
                  unsigned short* __restrict__ wtoff, unsigned short* __restrict__ wtg,
                  unsigned short* __restrict__ wtbe, unsigned short* __restrict__ wbd) {
    int idx = blockIdx.x * 256 + threadIdx.x;
    if (idx < 9 * 16 * 128) {
        int tap = idx / (16 * 128), oc = (idx / 128) % 16, ic = idx % 128;
        wt1[idx] = f2bf(w1[(oc * 128 + ic) * 9 + tap]);
    }
    if (idx < 9 * 64 * 32) {
        int tap = idx / (64 * 32), oc = (idx / 32) % 64, ic = idx % 32;
        wt2[idx] = (ic < 16) ? f2bf(w2[(oc * 16 + ic) * 9 + tap]) : (unsigned short)0;
    }
    if (idx < 9 * 32 * 64) {
        int tap = idx / (32 * 64), oc = (idx / 64) % 32, ic = idx % 64;
        wtoff[idx] = (oc < 27) ? f2bf(woff[(oc * 64 + ic) * 9 + tap]) : (unsigned short)0;
    }
    if (idx < 9 * 64 * 64) {
        int tap = idx / (64 * 64), oc = (idx / 64) % 64, ic = idx % 64;
        wtg[idx]  = f2bf(wg [(oc * 64 + ic) * 9 + tap]);
        wtbe[idx] = f2bf(wbe[(oc * 64 + ic) * 9 + tap]);
    }
    if (idx < 64 * 576) {
        int oc = idx / 576, r = idx - oc * 576;
        int tap = r >> 6, ic = r & 63;
        wbd[idx] = f2bf(wdcn[oc * 576 + ic * 9 + tap]);
    }
}

// ---------------------------------------------------------------------------
// transpose ref [b][c][p] -> refT [b][p][c]  (f32, channel-contiguous)
// ---------------------------------------------------------------------------
__global__ __launch_bounds__(256)
void transpose_ref(const float* __restrict__ ref, float* __restrict__ refT) {
    int idx = blockIdx.x * 256 + threadIdx.x;      // over B*HW*16
    if (idx >= B_ * HW_ * 16) return;
    int cg = idx & 15;
    int p  = (idx >> 4) % HW_;
    int b  = (idx >> 4) / HW_;
    const float* rb = ref + (size_t)b * SC_ * HW_ + p;
    float4 v;
    v.x = rb[(cg * 4 + 0) * HW_];
    v.y = rb[(cg * 4 + 1) * HW_];
    v.z = rb[(cg * 4 + 2) * HW_];
    v.w = rb[(cg * 4 + 3) * HW_];
    *reinterpret_cast<float4*>(&refT[((size_t)b * HW_ + p) * 64 + cg * 4]) = v;
}

// ---------------------------------------------------------------------------
// positional_norm (unchanged)
// ---------------------------------------------------------------------------
__global__ __launch_bounds__(256)
void norm_kernel(const float* __restrict__ x, float* __restrict__ nrm) {
    __shared__ float red1[4][64];
    __shared__ float red2[4][64];
    int blk = blockIdx.x;
    int b   = blk / 144;
    int p   = (blk % 144) * 64 + (threadIdx.x & 63);
    int cg  = threadIdx.x >> 6;

    float v[16];
    float s1 = 0.f, s2 = 0.f;
    const float* xb = x + ((size_t)b * NC_ + cg * 16) * HW_ + p;
    #pragma unroll
    for (int j = 0; j < 16; ++j) {
        v[j] = xb[j * HW_];
        s1 += v[j];
        s2 = fmaf(v[j], v[j], s2);
    }
    red1[cg][threadIdx.x & 63] = s1;
    red2[cg][threadIdx.x & 63] = s2;
    __syncthreads();
    int px = threadIdx.x & 63;
    s1 = red1[0][px] + red1[1][px] + red1[2][px] + red1[3][px];
    s2 = red2[0][px] + red2[1][px] + red2[2][px] + red2[3][px];
    float mean = s1 * (1.f / 64.f);
    float var  = (s2 - 64.f * mean * mean) * (1.f / 63.f);
    float inv  = 1.f / sqrtf(var + 1e-5f);
    float* nb = nrm + ((size_t)b * NC_ + cg * 16) * HW_ + p;
    #pragma unroll
    for (int j = 0; j < 16; ++j)
        nb[j * HW_] = (v[j] - mean) * inv;
}

// ---------------------------------------------------------------------------
// Tap-decomposed MFMA conv 3x3 (unchanged from round 5)
// ---------------------------------------------------------------------------
template <int CIN1, int CIN2, int ICP, int COLP, int COUT_PAD, int COUT_REAL,
          bool DUAL, bool RELU>
__global__ __launch_bounds__(256)
void conv_tap(const float* __restrict__ in1, const float* __restrict__ in2,
              const unsigned short* __restrict__ Wt,
              const unsigned short* __restrict__ Wt2,
              const float* __restrict__ bias, const float* __restrict__ bias2,
              const float* __restrict__ nrm, float* __restrict__ out) {
    constexpr int CIN  = CIN1 + CIN2;
    constexpr int NOCT = COUT_PAD / 16;
    constexpr int WPO  = 4 / NOCT;
    constexpr int MTP  = NOCT;
    constexpr int NACC = DUAL ? 2 : 1;
    constexpr int NKS  = ICP / 32;

    __shared__ unsigned short patch[6 * 18 * COLP];

    int t   = threadIdx.x;
    int blk = blockIdx.x;
    int bx  = blk % 6;
    int by  = (blk / 6) % 24;
    int b   = blk / 144;
    int x0  = bx * 16, y0 = by * 4;

    constexpr int NST = 6 * ICP * 18;
    for (int e = t; e < NST; e += 256) {
        int col = e % 18;
        int rem = e / 18;
        int ic  = rem % ICP;
        int row = rem / ICP;
        int yy = y0 + row - 1, xx = x0 + col - 1;
        float val = 0.f;
        if (ic < CIN && (unsigned)yy < (unsigned)H_ && (unsigned)xx < (unsigned)W_) {
            const float* src = (CIN2 == 0 || ic < CIN1)
                ? in1 + ((size_t)b * CIN1 + ic) * HW_
                : in2 + ((size_t)b * CIN2 + (ic - CIN1)) * HW_;
            val = src[yy * W_ + xx];
        }
        patch[(row * 18 + col) * COLP + ic] = f2bf(val);
    }
    __syncthreads();

    int wave = t >> 6, lane = t & 63;
    int fr = lane & 15, fq = lane >> 4;
    int oct  = wave / WPO;
    int widx = wave - oct * WPO;
    int mt0  = widx * MTP;

    f32x4 acc[MTP][NACC];
    #pragma unroll
    for (int i = 0; i < MTP; ++i)
        #pragma unroll
        for (int a = 0; a < NACC; ++a)
            acc[i][a] = (f32x4){0.f, 0.f, 0.f, 0.f};

    constexpr int dyv[9] = {0,0,0,1,1,1,2,2,2};
    constexpr int dxv[9] = {0,1,2,0,1,2,0,1,2};

    #pragma unroll
    for (int tap = 0; tap < 9; ++tap) {
        int dy = dyv[tap], dx = dxv[tap];
        #pragma unroll
        for (int ks = 0; ks < NKS; ++ks) {
            const size_t wo = ((size_t)tap * COUT_PAD + oct * 16 + fr) * ICP + ks * 32 + fq * 8;
            bf16x8 wfA = ld_frag(&Wt[wo]);
            bf16x8 wfB;
            if (DUAL) wfB = ld_frag(&Wt2[wo]);
            #pragma unroll
            for (int i = 0; i < MTP; ++i) {
                bf16x8 pf = ld_frag(&patch[((mt0 + i + dy) * 18 + (fr + dx)) * COLP
                                           + ks * 32 + fq * 8]);
                acc[i][0] = __builtin_amdgcn_mfma_f32_16x16x32_bf16(wfA, pf, acc[i][0], 0, 0, 0);
                if (DUAL)
                    acc[i][1] = __builtin_amdgcn_mfma_f32_16x16x32_bf16(wfB, pf, acc[i][1], 0, 0, 0);
            }
        }
    }

    #pragma unroll
    for (int i = 0; i < MTP; ++i) {
        int py = mt0 + i;
        #pragma unroll
        for (int j = 0; j < 4; ++j) {
            int oc = oct * 16 + fq * 4 + j;
            if (oc >= COUT_REAL) continue;
            size_t off = ((size_t)b * COUT_REAL + oc) * HW_ + (size_t)(y0 + py) * W_ + x0 + fr;
            float v = acc[i][0][j] + bias[oc];
            if (DUAL) {
                float be = acc[i][1][j] + bias2[oc];
                float nv = nrm[off];
                out[off] = fmaf(nv, 1.f + v, be);
            } else {
                out[off] = RELU ? fmaxf(v, 0.f) : v;
            }
        }
    }
}

// ---------------------------------------------------------------------------
// DCNv2 fused. Block = 16 px, 256 thr. Gather now reads refT (channel-
// contiguous): thread (pp = t>>4, cg = t&15); per tap k: 4 corner float4
// loads -> 16 lanes x float4 = 256 B contiguous per corner. 36 independent
// loads per thread, fully unrolled for ILP.
// ---------------------------------------------------------------------------
constexpr int SROW = 584;

__global__ __launch_bounds__(256)
void dcn_kernel(const float* __restrict__ refT, const float* __restrict__ om,
                const unsigned short* __restrict__ wbd, const float* __restrict__ b_dcn,
                float* __restrict__ out) {
    __shared__ unsigned short sS[16 * SROW];
    __shared__ float4 cwL[144];
    __shared__ int4   ciL[144];

    int t  = threadIdx.x;
    int b  = blockIdx.x / 576;
    int p0 = (blockIdx.x % 576) * 16;

    const float* refb = refT + (size_t)b * HW_ * 64;
    const float* omb  = om   + (size_t)b * 27 * HW_;

    // ---- phase 0: corner weights/indices ----
    if (t < 144) {
        int pp = t / 9, k = t - pp * 9;
        int p  = p0 + pp;
        int y  = p / W_, x = p - y * W_;
        float dy = omb[(2 * k)     * HW_ + p];
        float dx = omb[(2 * k + 1) * HW_ + p];
        float mk = omb[(18 + k)    * HW_ + p];
        mk = 1.f / (1.f + expf(-mk));

        float py = dy + (float)y + (float)(k / 3 - 1);
        float px = dx + (float)x + (float)(k % 3 - 1);
        float fy = floorf(py), fx = floorf(px);
        int   y0 = (int)fy,   x0 = (int)fx;
        float wy = py - fy,   wx = px - fx;

        float cw[4];
        int   ci[4];
        #pragma unroll
        for (int i = 0; i < 4; ++i) {
            int yy = y0 + (i >> 1);
            int xx = x0 + (i & 1);
            bool valid = (yy >= 0) && (yy < H_) && (xx >= 0) && (xx < W_);
            int yc = yy < 0 ? 0 : (yy > H_ - 1 ? H_ - 1 : yy);
            int xc = xx < 0 ? 0 : (xx > W_ - 1 ? W_ - 1 : xx);
            ci[i] = yc * W_ + xc;
            float wyi = (i >> 1) ? wy : (1.f - wy);
            float wxi = (i & 1)  ? wx : (1.f - wx);
            cw[i] = valid ? mk * wyi * wxi : 0.f;
        }
        cwL[t] = make_float4(cw[0], cw[1], cw[2], cw[3]);
        ciL[t] = make_int4(ci[0], ci[1], ci[2], ci[3]);
    }
    __syncthreads();

    // ---- phase 1: coalesced gather from refT ----
    {
        int pp = t >> 4, cg = t & 15;
        #pragma unroll
        for (int k = 0; k < 9; ++k) {
            float4 cw = cwL[pp * 9 + k];
            int4   ci = ciL[pp * 9 + k];
            const float4 a0 = *reinterpret_cast<const float4*>(&refb[(size_t)ci.x * 64 + cg * 4]);
            const float4 a1 = *reinterpret_cast<const float4*>(&refb[(size_t)ci.y * 64 + cg * 4]);
            const float4 a2 = *reinterpret_cast<const float4*>(&refb[(size_t)ci.z * 64 + cg * 4]);
            const float4 a3 = *reinterpret_cast<const float4*>(&refb[(size_t)ci.w * 64 + cg * 4]);
            float vx = cw.x * a0.x + cw.y * a1.x + cw.z * a2.x + cw.w * a3.x;
            float vy = cw.x * a0.y + cw.y * a1.y + cw.z * a2.y + cw.w * a3.y;
            float vz = cw.x * a0.z + cw.y * a1.z + cw.z * a2.z + cw.w * a3.z;
            float vw = cw.x * a0.w + cw.y * a1.w + cw.z * a2.w + cw.w * a3.w;
            ushort4 sv;
            sv.x = f2bf(vx); sv.y = f2bf(vy); sv.z = f2bf(vz); sv.w = f2bf(vw);
            *reinterpret_cast<ushort4*>(&sS[pp * SROW + k * 64 + cg * 4]) = sv;
        }
    }
    __syncthreads();

    // ---- phase 2: MFMA matvec ----
    int wave = t >> 6, lane = t & 63;
    int fr = lane & 15, fq = lane >> 4;

    f32x4 acc = (f32x4){0.f, 0.f, 0.f, 0.f};
    for (int ks = 0; ks < 18; ++ks) {
        bf16x8 wf = ld_frag(&wbd[(size_t)(wave * 16 + fr) * 576 + ks * 32 + fq * 8]);
        bf16x8 pf = ld_frag(&sS[(size_t)fr * SROW + ks * 32 + fq * 8]);
        acc = __builtin_amdgcn_mfma_f32_16x16x32_bf16(wf, pf, acc, 0, 0, 0);
    }

    float* outb = out + (size_t)b * SC_ * HW_;
    #pragma unroll
    for (int j = 0; j < 4; ++j) {
        int oc = wave * 16 + fq * 4 + j;
        outb[(size_t)oc * HW_ + p0 + fr] = acc[j] + b_dcn[oc];
    }
}

} // namespace

// ---------------------------------------------------------------------------
extern "C" void kernel_launch(void* const* d_in, const int* in_sizes, int n_in,
                              void* d_out, int out_size, void* d_ws, size_t ws_size,
                              hipStream_t stream) {
    (void)in_sizes; (void)n_in; (void)out_size; (void)ws_size;

    const float* x     = (const float*)d_in[0];
    const float* ref   = (const float*)d_in[1];
    const float* w1    = (const float*)d_in[2];
    const float* b1    = (const float*)d_in[3];
    const float* w2    = (const float*)d_in[4];
    const float* b2    = (const float*)d_in[5];
    const float* w_off = (const float*)d_in[6];
    const float* b_off = (const float*)d_in[7];
    const float* w_dcn = (const float*)d_in[8];
    const float* b_dcn = (const float*)d_in[9];
    const float* w_g   = (const float*)d_in[10];
    const float* b_g   = (const float*)d_in[11];
    const float* w_be  = (const float*)d_in[12];
    const float* b_be  = (const float*)d_in[13];

    float* out = (float*)d_out;
    float* ws  = (float*)d_ws;

    float* nrm   = ws;                      // 1,179,648 f
    float* hmid  = nrm   + 1179648;         //   294,912 f
    float* cond  = hmid  + 294912;          // 1,179,648 f
    float* om    = cond  + 1179648;         //   497,664 f
    float* rr    = om    + 497664;          // 1,179,648 f
    float* refTT = rr    + 1179648;         // 1,179,648 f
    unsigned short* wt1   = (unsigned short*)(refTT + 1179648); // 18,432
    unsigned short* wt2   = wt1   + 18432;                      // 18,432
    unsigned short* wtoff = wt2   + 18432;                      // 18,432
    unsigned short* wtg   = wtoff + 18432;                      // 36,864
    unsigned short* wtbe  = wtg   + 36864;                      // 36,864
    unsigned short* wbd   = wtbe  + 36864;                      // 36,864

    prep_weights<<<144, 256, 0, stream>>>(w1, w2, w_off, w_g, w_be, w_dcn,
                                          wt1, wt2, wtoff, wtg, wtbe, wbd);

    transpose_ref<<<(B_ * HW_ * 16 + 255) / 256, 256, 0, stream>>>(ref, refTT);

    norm_kernel<<<288, 256, 0, stream>>>(x, nrm);

    constexpr int GRID = 288;

    // conv1: 128 -> 16, ReLU. ICP=128, COLP=136.
    conv_tap<64, 64, 128, 136, 16, 16, false, true>
        <<<GRID, 256, 0, stream>>>(nrm, ref, wt1, nullptr, b1, nullptr, nullptr, hmid);

    // conv2: 16 -> 64, ReLU. ICP=32, COLP=40.
    conv_tap<16, 0, 32, 40, 64, 64, false, true>
        <<<GRID, 256, 0, stream>>>(hmid, nullptr, wt2, nullptr, b2, nullptr, nullptr, cond);

    // conv_off: 64 -> 27 (pad 32). ICP=64, COLP=72.
    conv_tap<64, 0, 64, 72, 32, 27, false, false>
        <<<GRID, 256, 0, stream>>>(cond, nullptr, wtoff, nullptr, b_off, nullptr, nullptr, om);

    dcn_kernel<<<B_ * 576, 256, 0, stream>>>(refTT, om, wbd, b_dcn, rr);

    // final: gamma/beta DUAL + fused affine epilogue. ICP=64, COLP=72.
    conv_tap<64, 0, 64, 72, 64, 64, true, false>
        <<<GRID, 256, 0, stream>>>(rr, nullptr, wtg, wtbe, b_g, b_be, nrm, out);
}

// Round 7
// 83.806 us; speedup vs baseline: 4.1631x; 1.4836x over previous
//
#include <hip/hip_runtime.h>
#include <math.h>

namespace {

typedef __attribute__((ext_vector_type(8))) short          bf16x8;
typedef __attribute__((ext_vector_type(8))) unsigned short u16x8;
typedef __attribute__((ext_vector_type(4))) float          f32x4;

constexpr int B_  = 2;
constexpr int H_  = 96;
constexpr int W_  = 96;
constexpr int HW_ = H_ * W_;
constexpr int NC_ = 64;
constexpr int SC_ = 64;

__device__ inline unsigned short f2bf(float f) {
    union { float f; unsigned u; } v; v.f = f;
    unsigned r = v.u + 0x7FFFu + ((v.u >> 16) & 1u);
    return (unsigned short)(r >> 16);
}

__device__ inline bf16x8 ld_frag(const unsigned short* p) {
    return *reinterpret_cast<const bf16x8*>(p);
}

// ---------------------------------------------------------------------------
// prep: weights -> bf16, tap-major [tap][ocp][icp] (unchanged from round 5/6)
// ---------------------------------------------------------------------------
__global__ __launch_bounds__(256)
void prep_weights(const float* __restrict__ w1, const float* __restrict__ w2,
                  const float* __restrict__ woff, const float* __restrict__ wg,
                  const float* __restrict__ wbe, const float* __restrict__ wdcn,
                  unsigned short* __restrict__ wt1, unsigned short* __restrict__ wt2,
                  unsigned short* __restrict__ wtoff, unsigned short* __restrict__ wtg,
                  unsigned short* __restrict__ wtbe, unsigned short* __restrict__ wbd) {
    int idx = blockIdx.x * 256 + threadIdx.x;
    if (idx < 9 * 16 * 128) {
        int tap = idx / (16 * 128), oc = (idx / 128) % 16, ic = idx % 128;
        wt1[idx] = f2bf(w1[(oc * 128 + ic) * 9 + tap]);
    }
    if (idx < 9 * 64 * 32) {
        int tap = idx / (64 * 32), oc = (idx / 32) % 64, ic = idx % 32;
        wt2[idx] = (ic < 16) ? f2bf(w2[(oc * 16 + ic) * 9 + tap]) : (unsigned short)0;
    }
    if (idx < 9 * 32 * 64) {
        int tap = idx / (32 * 64), oc = (idx / 64) % 32, ic = idx % 64;
        wtoff[idx] = (oc < 27) ? f2bf(woff[(oc * 64 + ic) * 9 + tap]) : (unsigned short)0;
    }
    if (idx < 9 * 64 * 64) {
        int tap = idx / (64 * 64), oc = (idx / 64) % 64, ic = idx % 64;
        wtg[idx]  = f2bf(wg [(oc * 64 + ic) * 9 + tap]);
        wtbe[idx] = f2bf(wbe[(oc * 64 + ic) * 9 + tap]);
    }
    if (idx < 64 * 576) {
        int oc = idx / 576, r = idx - oc * 576;
        int tap = r >> 6, ic = r & 63;
        wbd[idx] = f2bf(wdcn[oc * 576 + ic * 9 + tap]);
    }
}

// ---------------------------------------------------------------------------
// transpose ref: refT f32 [b][p][64] (dcn gather)  +  cc[p][64..128) bf16
// ---------------------------------------------------------------------------
__global__ __launch_bounds__(256)
void transpose_ref(const float* __restrict__ ref, float* __restrict__ refT,
                   unsigned short* __restrict__ cc) {
    int idx = blockIdx.x * 256 + threadIdx.x;      // over B*HW*16
    if (idx >= B_ * HW_ * 16) return;
    int cg = idx & 15;
    int p  = (idx >> 4) % HW_;
    int b  = (idx >> 4) / HW_;
    const float* rb = ref + (size_t)b * SC_ * HW_ + p;
    float4 v;
    v.x = rb[(cg * 4 + 0) * HW_];
    v.y = rb[(cg * 4 + 1) * HW_];
    v.z = rb[(cg * 4 + 2) * HW_];
    v.w = rb[(cg * 4 + 3) * HW_];
    size_t bp = (size_t)b * HW_ + p;
    *reinterpret_cast<float4*>(&refT[bp * 64 + cg * 4]) = v;
    ushort4 s;
    s.x = f2bf(v.x); s.y = f2bf(v.y); s.z = f2bf(v.z); s.w = f2bf(v.w);
    *reinterpret_cast<ushort4*>(&cc[bp * 128 + 64 + cg * 4]) = s;
}

// ---------------------------------------------------------------------------
// positional_norm: nrm f32 [c][p] (final epilogue) + cc[p][0..64) bf16 (conv1)
// ---------------------------------------------------------------------------
__global__ __launch_bounds__(256)
void norm_kernel(const float* __restrict__ x, float* __restrict__ nrm,
                 unsigned short* __restrict__ cc) {
    __shared__ float red1[4][64];
    __shared__ float red2[4][64];
    int blk = blockIdx.x;
    int b   = blk / 144;
    int p   = (blk % 144) * 64 + (threadIdx.x & 63);
    int cg  = threadIdx.x >> 6;

    float v[16];
    float s1 = 0.f, s2 = 0.f;
    const float* xb = x + ((size_t)b * NC_ + cg * 16) * HW_ + p;
    #pragma unroll
    for (int j = 0; j < 16; ++j) {
        v[j] = xb[j * HW_];
        s1 += v[j];
        s2 = fmaf(v[j], v[j], s2);
    }
    red1[cg][threadIdx.x & 63] = s1;
    red2[cg][threadIdx.x & 63] = s2;
    __syncthreads();
    int px = threadIdx.x & 63;
    s1 = red1[0][px] + red1[1][px] + red1[2][px] + red1[3][px];
    s2 = red2[0][px] + red2[1][px] + red2[2][px] + red2[3][px];
    float mean = s1 * (1.f / 64.f);
    float var  = (s2 - 64.f * mean * mean) * (1.f / 63.f);
    float inv  = 1.f / sqrtf(var + 1e-5f);
    float* nb = nrm + ((size_t)b * NC_ + cg * 16) * HW_ + p;
    u16x8 pk[2];
    #pragma unroll
    for (int j = 0; j < 16; ++j) {
        float nv = (v[j] - mean) * inv;
        nb[j * HW_] = nv;
        pk[j >> 3][j & 7] = f2bf(nv);
    }
    size_t bp = (size_t)b * HW_ + p;
    *reinterpret_cast<u16x8*>(&cc[bp * 128 + cg * 16 + 0]) = pk[0];
    *reinterpret_cast<u16x8*>(&cc[bp * 128 + cg * 16 + 8]) = pk[1];
}

// ---------------------------------------------------------------------------
// Tap-decomposed MFMA conv 3x3, pad 1, bf16 [p][ICS] input.
// Stage patch once: bounds-checked bf16x8 copies (vectorized).
// OUTBF: store bf16 [p][COUT_REAL] (ushort4/lane); else f32 [c][p] (+DUAL).
// ---------------------------------------------------------------------------
template <int ICS, int ICP, int COLP, int COUT_PAD, int COUT_REAL,
          bool DUAL, bool RELU, bool OUTBF>
__global__ __launch_bounds__(256)
void conv_bf(const unsigned short* __restrict__ in,
             const unsigned short* __restrict__ Wt,
             const unsigned short* __restrict__ Wt2,
             const float* __restrict__ bias, const float* __restrict__ bias2,
             const float* __restrict__ nrm, float* __restrict__ outF,
             unsigned short* __restrict__ outB) {
    constexpr int NOCT = COUT_PAD / 16;
    constexpr int WPO  = 4 / NOCT;
    constexpr int MTP  = NOCT;
    constexpr int NACC = DUAL ? 2 : 1;
    constexpr int NKS  = ICP / 32;
    constexpr int NCH8 = ICP / 8;

    __shared__ unsigned short patch[6 * 18 * COLP];

    int t   = threadIdx.x;
    int blk = blockIdx.x;                 // 288 = B * 24 * 6
    int bx  = blk % 6;
    int by  = (blk / 6) % 24;
    int b   = blk / 144;
    int x0  = bx * 16, y0 = by * 4;

    // ---- stage patch: vector bf16x8 copies ----
    for (int e = t; e < 6 * 18 * NCH8; e += 256) {
        int kc  = e % NCH8;
        int col = (e / NCH8) % 18;
        int row = e / (NCH8 * 18);
        int yy = y0 + row - 1, xx = x0 + col - 1;
        bf16x8 v = (bf16x8){0, 0, 0, 0, 0, 0, 0, 0};
        if (kc * 8 < ICS && (unsigned)yy < (unsigned)H_ && (unsigned)xx < (unsigned)W_) {
            v = ld_frag(&in[((size_t)b * HW_ + yy * W_ + xx) * ICS + kc * 8]);
        }
        *reinterpret_cast<bf16x8*>(&patch[(row * 18 + col) * COLP + kc * 8]) = v;
    }
    __syncthreads();

    // ---- MFMA: 9 taps x NKS k-steps x MTP m-tiles ----
    int wave = t >> 6, lane = t & 63;
    int fr = lane & 15, fq = lane >> 4;
    int oct  = wave / WPO;
    int widx = wave - oct * WPO;
    int mt0  = widx * MTP;

    f32x4 acc[MTP][NACC];
    #pragma unroll
    for (int i = 0; i < MTP; ++i)
        #pragma unroll
        for (int a = 0; a < NACC; ++a)
            acc[i][a] = (f32x4){0.f, 0.f, 0.f, 0.f};

    constexpr int dyv[9] = {0,0,0,1,1,1,2,2,2};
    constexpr int dxv[9] = {0,1,2,0,1,2,0,1,2};

    #pragma unroll
    for (int tap = 0; tap < 9; ++tap) {
        int dy = dyv[tap], dx = dxv[tap];
        #pragma unroll
        for (int ks = 0; ks < NKS; ++ks) {
            const size_t wo = ((size_t)tap * COUT_PAD + oct * 16 + fr) * ICP + ks * 32 + fq * 8;
            bf16x8 wfA = ld_frag(&Wt[wo]);
            bf16x8 wfB;
            if (DUAL) wfB = ld_frag(&Wt2[wo]);
            #pragma unroll
            for (int i = 0; i < MTP; ++i) {
                bf16x8 pf = ld_frag(&patch[((mt0 + i + dy) * 18 + (fr + dx)) * COLP
                                           + ks * 32 + fq * 8]);
                acc[i][0] = __builtin_amdgcn_mfma_f32_16x16x32_bf16(wfA, pf, acc[i][0], 0, 0, 0);
                if (DUAL)
                    acc[i][1] = __builtin_amdgcn_mfma_f32_16x16x32_bf16(wfB, pf, acc[i][1], 0, 0, 0);
            }
        }
    }

    // ---- store ----
    #pragma unroll
    for (int i = 0; i < MTP; ++i) {
        int py = mt0 + i;
        if (OUTBF) {
            // bf16 [p][COUT_REAL]; COUT_PAD == COUT_REAL in all OUTBF uses
            size_t p = (size_t)b * HW_ + (size_t)(y0 + py) * W_ + x0 + fr;
            ushort4 sv;
            #pragma unroll
            for (int j = 0; j < 4; ++j) {
                float v = acc[i][0][j] + bias[oct * 16 + fq * 4 + j];
                if (RELU) v = fmaxf(v, 0.f);
                ((unsigned short*)&sv)[j] = f2bf(v);
            }
            *reinterpret_cast<ushort4*>(&outB[p * COUT_REAL + oct * 16 + fq * 4]) = sv;
        } else {
            #pragma unroll
            for (int j = 0; j < 4; ++j) {
                int oc = oct * 16 + fq * 4 + j;
                if (oc >= COUT_REAL) continue;
                size_t off = ((size_t)b * COUT_REAL + oc) * HW_
                           + (size_t)(y0 + py) * W_ + x0 + fr;
                float v = acc[i][0][j] + bias[oc];
                if (DUAL) {
                    float be = acc[i][1][j] + bias2[oc];
                    float nv = nrm[off];
                    outF[off] = fmaf(nv, 1.f + v, be);
                } else {
                    outF[off] = RELU ? fmaxf(v, 0.f) : v;
                }
            }
        }
    }
}

// ---------------------------------------------------------------------------
// DCNv2 fused (round-6 gather); output now bf16 [p][64] for the final conv.
// ---------------------------------------------------------------------------
constexpr int SROW = 584;

__global__ __launch_bounds__(256)
void dcn_kernel(const float* __restrict__ refT, const float* __restrict__ om,
                const unsigned short* __restrict__ wbd, const float* __restrict__ b_dcn,
                unsigned short* __restrict__ rrT) {
    __shared__ unsigned short sS[16 * SROW];
    __shared__ float4 cwL[144];
    __shared__ int4   ciL[144];

    int t  = threadIdx.x;
    int b  = blockIdx.x / 576;
    int p0 = (blockIdx.x % 576) * 16;

    const float* refb = refT + (size_t)b * HW_ * 64;
    const float* omb  = om   + (size_t)b * 27 * HW_;

    if (t < 144) {
        int pp = t / 9, k = t - pp * 9;
        int p  = p0 + pp;
        int y  = p / W_, x = p - y * W_;
        float dy = omb[(2 * k)     * HW_ + p];
        float dx = omb[(2 * k + 1) * HW_ + p];
        float mk = omb[(18 + k)    * HW_ + p];
        mk = 1.f / (1.f + expf(-mk));

        float py = dy + (float)y + (float)(k / 3 - 1);
        float px = dx + (float)x + (float)(k % 3 - 1);
        float fy = floorf(py), fx = floorf(px);
        int   y0 = (int)fy,   x0 = (int)fx;
        float wy = py - fy,   wx = px - fx;

        float cw[4];
        int   ci[4];
        #pragma unroll
        for (int i = 0; i < 4; ++i) {
            int yy = y0 + (i >> 1);
            int xx = x0 + (i & 1);
            bool valid = (yy >= 0) && (yy < H_) && (xx >= 0) && (xx < W_);
            int yc = yy < 0 ? 0 : (yy > H_ - 1 ? H_ - 1 : yy);
            int xc = xx < 0 ? 0 : (xx > W_ - 1 ? W_ - 1 : xx);
            ci[i] = yc * W_ + xc;
            float wyi = (i >> 1) ? wy : (1.f - wy);
            float wxi = (i & 1)  ? wx : (1.f - wx);
            cw[i] = valid ? mk * wyi * wxi : 0.f;
        }
        cwL[t] = make_float4(cw[0], cw[1], cw[2], cw[3]);
        ciL[t] = make_int4(ci[0], ci[1], ci[2], ci[3]);
    }
    __syncthreads();

    {
        int pp = t >> 4, cg = t & 15;
        #pragma unroll
        for (int k = 0; k < 9; ++k) {
            float4 cw = cwL[pp * 9 + k];
            int4   ci = ciL[pp * 9 + k];
            const float4 a0 = *reinterpret_cast<const float4*>(&refb[(size_t)ci.x * 64 + cg * 4]);
            const float4 a1 = *reinterpret_cast<const float4*>(&refb[(size_t)ci.y * 64 + cg * 4]);
            const float4 a2 = *reinterpret_cast<const float4*>(&refb[(size_t)ci.z * 64 + cg * 4]);
            const float4 a3 = *reinterpret_cast<const float4*>(&refb[(size_t)ci.w * 64 + cg * 4]);
            float vx = cw.x * a0.x + cw.y * a1.x + cw.z * a2.x + cw.w * a3.x;
            float vy = cw.x * a0.y + cw.y * a1.y + cw.z * a2.y + cw.w * a3.y;
            float vz = cw.x * a0.z + cw.y * a1.z + cw.z * a2.z + cw.w * a3.z;
            float vw = cw.x * a0.w + cw.y * a1.w + cw.z * a2.w + cw.w * a3.w;
            ushort4 sv;
            sv.x = f2bf(vx); sv.y = f2bf(vy); sv.z = f2bf(vz); sv.w = f2bf(vw);
            *reinterpret_cast<ushort4*>(&sS[pp * SROW + k * 64 + cg * 4]) = sv;
        }
    }
    __syncthreads();

    int wave = t >> 6, lane = t & 63;
    int fr = lane & 15, fq = lane >> 4;

    f32x4 acc = (f32x4){0.f, 0.f, 0.f, 0.f};
    for (int ks = 0; ks < 18; ++ks) {
        bf16x8 wf = ld_frag(&wbd[(size_t)(wave * 16 + fr) * 576 + ks * 32 + fq * 8]);
        bf16x8 pf = ld_frag(&sS[(size_t)fr * SROW + ks * 32 + fq * 8]);
        acc = __builtin_amdgcn_mfma_f32_16x16x32_bf16(wf, pf, acc, 0, 0, 0);
    }

    // bf16 [p][64] packed store
    {
        size_t p = (size_t)b * HW_ + p0 + fr;
        ushort4 sv;
        #pragma unroll
        for (int j = 0; j < 4; ++j)
            ((unsigned short*)&sv)[j] = f2bf(acc[j] + b_dcn[wave * 16 + fq * 4 + j]);
        *reinterpret_cast<ushort4*>(&rrT[p * 64 + wave * 16 + fq * 4]) = sv;
    }
}

} // namespace

// ---------------------------------------------------------------------------
extern "C" void kernel_launch(void* const* d_in, const int* in_sizes, int n_in,
                              void* d_out, int out_size, void* d_ws, size_t ws_size,
                              hipStream_t stream) {
    (void)in_sizes; (void)n_in; (void)out_size; (void)ws_size;

    const float* x     = (const float*)d_in[0];
    const float* ref   = (const float*)d_in[1];
    const float* w1    = (const float*)d_in[2];
    const float* b1    = (const float*)d_in[3];
    const float* w2    = (const float*)d_in[4];
    const float* b2    = (const float*)d_in[5];
    const float* w_off = (const float*)d_in[6];
    const float* b_off = (const float*)d_in[7];
    const float* w_dcn = (const float*)d_in[8];
    const float* b_dcn = (const float*)d_in[9];
    const float* w_g   = (const float*)d_in[10];
    const float* b_g   = (const float*)d_in[11];
    const float* w_be  = (const float*)d_in[12];
    const float* b_be  = (const float*)d_in[13];

    float* out = (float*)d_out;
    float* ws  = (float*)d_ws;

    // f32 buffers
    float* nrm  = ws;                       // 1,179,648 f   [b][c][p]
    float* om   = nrm  + 1179648;           //   497,664 f   [b][27][p]
    float* refT = om   + 497664;            // 1,179,648 f   [b][p][64]
    // bf16 buffers
    unsigned short* cc    = (unsigned short*)(refT + 1179648); // [b][p][128]  2,359,296
    unsigned short* hmidT = cc    + 2359296;                   // [b][p][16]     294,912
    unsigned short* condT = hmidT + 294912;                    // [b][p][64]   1,179,648
    unsigned short* rrT   = condT + 1179648;                   // [b][p][64]   1,179,648
    // weights
    unsigned short* wt1   = rrT   + 1179648;                   // 18,432
    unsigned short* wt2   = wt1   + 18432;                     // 18,432
    unsigned short* wtoff = wt2   + 18432;                     // 18,432
    unsigned short* wtg   = wtoff + 18432;                     // 36,864
    unsigned short* wtbe  = wtg   + 36864;                     // 36,864
    unsigned short* wbd   = wtbe  + 36864;                     // 36,864

    prep_weights<<<144, 256, 0, stream>>>(w1, w2, w_off, w_g, w_be, w_dcn,
                                          wt1, wt2, wtoff, wtg, wtbe, wbd);

    transpose_ref<<<(B_ * HW_ * 16 + 255) / 256, 256, 0, stream>>>(ref, refT, cc);

    norm_kernel<<<288, 256, 0, stream>>>(x, nrm, cc);

    constexpr int GRID = 288;

    // conv1: cc[p][128] -> hmidT[p][16], ReLU
    conv_bf<128, 128, 136, 16, 16, false, true, true>
        <<<GRID, 256, 0, stream>>>(cc, wt1, nullptr, b1, nullptr, nullptr, nullptr, hmidT);

    // conv2: hmidT[p][16] -> condT[p][64], ReLU (ICP=32, upper 16 zero)
    conv_bf<16, 32, 40, 64, 64, false, true, true>
        <<<GRID, 256, 0, stream>>>(hmidT, wt2, nullptr, b2, nullptr, nullptr, nullptr, condT);

    // conv_off: condT[p][64] -> om f32 [27][p]
    conv_bf<64, 64, 72, 32, 27, false, false, false>
        <<<GRID, 256, 0, stream>>>(condT, wtoff, nullptr, b_off, nullptr, nullptr, om, nullptr);

    dcn_kernel<<<B_ * 576, 256, 0, stream>>>(refT, om, wbd, b_dcn, rrT);

    // final: rrT[p][64] -> out f32 [64][p], gamma/beta DUAL + affine epilogue
    conv_bf<64, 64, 72, 64, 64, true, false, false>
        <<<GRID, 256, 0, stream>>>(rrT, wtg, wtbe, b_g, b_be, nrm, out, nullptr);
}

// Round 8
// 73.761 us; speedup vs baseline: 4.7300x; 1.1362x over previous
//
#include <hip/hip_runtime.h>
#include <math.h>

namespace {

typedef __attribute__((ext_vector_type(8))) short          bf16x8;
typedef __attribute__((ext_vector_type(8))) unsigned short u16x8;
typedef __attribute__((ext_vector_type(4))) float          f32x4;

constexpr int B_  = 2;
constexpr int H_  = 96;
constexpr int W_  = 96;
constexpr int HW_ = H_ * W_;
constexpr int NC_ = 64;
constexpr int SC_ = 64;

__device__ inline unsigned short f2bf(float f) {
    union { float f; unsigned u; } v; v.f = f;
    unsigned r = v.u + 0x7FFFu + ((v.u >> 16) & 1u);
    return (unsigned short)(r >> 16);
}
__device__ inline float bf2f(unsigned short s) {
    union { unsigned u; float f; } v; v.u = ((unsigned)s) << 16; return v.f;
}
__device__ inline bf16x8 ld_frag(const unsigned short* p) {
    return *reinterpret_cast<const bf16x8*>(p);
}

// ---------------------------------------------------------------------------
// prologue (grid 432):
//  blocks 0..287  : positional_norm (nrm f32 [c][p] + cc[p][0..64) bf16)
//                   + ref transpose via LDS tile (cc[p][64..128) bf16)
//  blocks 288..431: weight prep -> bf16 tap-major [tap][ocp][icp] + wbd
// ---------------------------------------------------------------------------
__global__ __launch_bounds__(256)
void prologue(const float* __restrict__ x, const float* __restrict__ ref,
              const float* __restrict__ w1, const float* __restrict__ w2,
              const float* __restrict__ woff, const float* __restrict__ wg,
              const float* __restrict__ wbe, const float* __restrict__ wdcn,
              float* __restrict__ nrm, unsigned short* __restrict__ cc,
              unsigned short* __restrict__ wt1, unsigned short* __restrict__ wt2,
              unsigned short* __restrict__ wtoff, unsigned short* __restrict__ wtg,
              unsigned short* __restrict__ wtbe, unsigned short* __restrict__ wbd) {
    __shared__ float red1[4][64];
    __shared__ float red2[4][64];
    __shared__ float rtile[64][65];       // ref tile [ch][px]

    int blk = blockIdx.x;
    int t   = threadIdx.x;

    if (blk < 288) {
        int b  = blk / 144;
        int p0 = (blk % 144) * 64;
        int px = t & 63;
        int cg = t >> 6;                  // 0..3
        int p  = p0 + px;

        // ---- norm loads + partial reduce; ref -> LDS tile ----
        float v[16];
        float s1 = 0.f, s2 = 0.f;
        const float* xb = x + ((size_t)b * NC_ + cg * 16) * HW_ + p;
        #pragma unroll
        for (int j = 0; j < 16; ++j) {
            v[j] = xb[j * HW_];
            s1 += v[j];
            s2 = fmaf(v[j], v[j], s2);
        }
        red1[cg][px] = s1;
        red2[cg][px] = s2;

        const float* rb = ref + (size_t)b * SC_ * HW_ + p0 + px;
        #pragma unroll
        for (int it = 0; it < 16; ++it) {
            int ch = it * 4 + cg;
            rtile[ch][px] = rb[(size_t)ch * HW_];
        }
        __syncthreads();

        // ---- norm finish: nrm f32 + cc[0..64) bf16 ----
        s1 = red1[0][px] + red1[1][px] + red1[2][px] + red1[3][px];
        s2 = red2[0][px] + red2[1][px] + red2[2][px] + red2[3][px];
        float mean = s1 * (1.f / 64.f);
        float var  = (s2 - 64.f * mean * mean) * (1.f / 63.f);
        float inv  = 1.f / sqrtf(var + 1e-5f);
        float* nb = nrm + ((size_t)b * NC_ + cg * 16) * HW_ + p;
        u16x8 pk[2];
        #pragma unroll
        for (int j = 0; j < 16; ++j) {
            float nv = (v[j] - mean) * inv;
            nb[j * HW_] = nv;
            pk[j >> 3][j & 7] = f2bf(nv);
        }
        size_t bp = (size_t)b * HW_ + p;
        *reinterpret_cast<u16x8*>(&cc[bp * 128 + cg * 16 + 0]) = pk[0];
        *reinterpret_cast<u16x8*>(&cc[bp * 128 + cg * 16 + 8]) = pk[1];

        // ---- ref transpose writer: cc[64..128) bf16, fully coalesced ----
        {
            int wpx = t >> 2, q = t & 3;
            size_t bp2 = (size_t)b * HW_ + p0 + wpx;
            u16x8 o0, o1;
            #pragma unroll
            for (int j = 0; j < 8; ++j) {
                o0[j] = f2bf(rtile[q * 16 + j][wpx]);
                o1[j] = f2bf(rtile[q * 16 + 8 + j][wpx]);
            }
            *reinterpret_cast<u16x8*>(&cc[bp2 * 128 + 64 + q * 16 + 0]) = o0;
            *reinterpret_cast<u16x8*>(&cc[bp2 * 128 + 64 + q * 16 + 8]) = o1;
        }
    } else {
        int idx = (blk - 288) * 256 + t;
        if (idx < 9 * 16 * 128) {
            int tap = idx / (16 * 128), oc = (idx / 128) % 16, ic = idx % 128;
            wt1[idx] = f2bf(w1[(oc * 128 + ic) * 9 + tap]);
        }
        if (idx < 9 * 64 * 32) {
            int tap = idx / (64 * 32), oc = (idx / 32) % 64, ic = idx % 32;
            wt2[idx] = (ic < 16) ? f2bf(w2[(oc * 16 + ic) * 9 + tap]) : (unsigned short)0;
        }
        if (idx < 9 * 32 * 64) {
            int tap = idx / (32 * 64), oc = (idx / 64) % 32, ic = idx % 64;
            wtoff[idx] = (oc < 27) ? f2bf(woff[(oc * 64 + ic) * 9 + tap]) : (unsigned short)0;
        }
        if (idx < 9 * 64 * 64) {
            int tap = idx / (64 * 64), oc = (idx / 64) % 64, ic = idx % 64;
            wtg[idx]  = f2bf(wg [(oc * 64 + ic) * 9 + tap]);
            wtbe[idx] = f2bf(wbe[(oc * 64 + ic) * 9 + tap]);
        }
        if (idx < 64 * 576) {
            int oc = idx / 576, r = idx - oc * 576;
            int tap = r >> 6, ic = r & 63;
            wbd[idx] = f2bf(wdcn[oc * 576 + ic * 9 + tap]);
        }
    }
}

// ---------------------------------------------------------------------------
// Tap-decomposed MFMA conv 3x3, pad 1, bf16 [p][ICS] input.
// OMODE 0: f32 [c][p] (+DUAL affine epilogue) | 1: bf16 [p][COUT_REAL]
//       2: f32 px-major [p][32] (for om)
// ---------------------------------------------------------------------------
template <int ICS, int ICP, int COLP, int COUT_PAD, int COUT_REAL,
          bool DUAL, bool RELU, int OMODE>
__global__ __launch_bounds__(256)
void conv_bf(const unsigned short* __restrict__ in,
             const unsigned short* __restrict__ Wt,
             const unsigned short* __restrict__ Wt2,
             const float* __restrict__ bias, const float* __restrict__ bias2,
             const float* __restrict__ nrm, float* __restrict__ outF,
             unsigned short* __restrict__ outB) {
    constexpr int NOCT = COUT_PAD / 16;
    constexpr int WPO  = 4 / NOCT;
    constexpr int MTP  = NOCT;
    constexpr int NACC = DUAL ? 2 : 1;
    constexpr int NKS  = ICP / 32;
    constexpr int NCH8 = ICP / 8;

    __shared__ unsigned short patch[6 * 18 * COLP];

    int t   = threadIdx.x;
    int blk = blockIdx.x;                 // 288 = B * 24 * 6
    int bx  = blk % 6;
    int by  = (blk / 6) % 24;
    int b   = blk / 144;
    int x0  = bx * 16, y0 = by * 4;

    // ---- stage patch: vector bf16x8 copies ----
    for (int e = t; e < 6 * 18 * NCH8; e += 256) {
        int kc  = e % NCH8;
        int col = (e / NCH8) % 18;
        int row = e / (NCH8 * 18);
        int yy = y0 + row - 1, xx = x0 + col - 1;
        bf16x8 v = (bf16x8){0, 0, 0, 0, 0, 0, 0, 0};
        if (kc * 8 < ICS && (unsigned)yy < (unsigned)H_ && (unsigned)xx < (unsigned)W_) {
            v = ld_frag(&in[((size_t)b * HW_ + yy * W_ + xx) * ICS + kc * 8]);
        }
        *reinterpret_cast<bf16x8*>(&patch[(row * 18 + col) * COLP + kc * 8]) = v;
    }
    __syncthreads();

    // ---- MFMA: 9 taps x NKS k-steps x MTP m-tiles ----
    int wave = t >> 6, lane = t & 63;
    int fr = lane & 15, fq = lane >> 4;
    int oct  = wave / WPO;
    int widx = wave - oct * WPO;
    int mt0  = widx * MTP;

    f32x4 acc[MTP][NACC];
    #pragma unroll
    for (int i = 0; i < MTP; ++i)
        #pragma unroll
        for (int a = 0; a < NACC; ++a)
            acc[i][a] = (f32x4){0.f, 0.f, 0.f, 0.f};

    constexpr int dyv[9] = {0,0,0,1,1,1,2,2,2};
    constexpr int dxv[9] = {0,1,2,0,1,2,0,1,2};

    #pragma unroll
    for (int tap = 0; tap < 9; ++tap) {
        int dy = dyv[tap], dx = dxv[tap];
        #pragma unroll
        for (int ks = 0; ks < NKS; ++ks) {
            const size_t wo = ((size_t)tap * COUT_PAD + oct * 16 + fr) * ICP + ks * 32 + fq * 8;
            bf16x8 wfA = ld_frag(&Wt[wo]);
            bf16x8 wfB;
            if (DUAL) wfB = ld_frag(&Wt2[wo]);
            #pragma unroll
            for (int i = 0; i < MTP; ++i) {
                bf16x8 pf = ld_frag(&patch[((mt0 + i + dy) * 18 + (fr + dx)) * COLP
                                           + ks * 32 + fq * 8]);
                acc[i][0] = __builtin_amdgcn_mfma_f32_16x16x32_bf16(wfA, pf, acc[i][0], 0, 0, 0);
                if (DUAL)
                    acc[i][1] = __builtin_amdgcn_mfma_f32_16x16x32_bf16(wfB, pf, acc[i][1], 0, 0, 0);
            }
        }
    }

    // ---- store ----
    #pragma unroll
    for (int i = 0; i < MTP; ++i) {
        int py = mt0 + i;
        if (OMODE == 1) {
            size_t p = (size_t)b * HW_ + (size_t)(y0 + py) * W_ + x0 + fr;
            ushort4 sv;
            #pragma unroll
            for (int j = 0; j < 4; ++j) {
                float v = acc[i][0][j] + bias[oct * 16 + fq * 4 + j];
                if (RELU) v = fmaxf(v, 0.f);
                ((unsigned short*)&sv)[j] = f2bf(v);
            }
            *reinterpret_cast<ushort4*>(&outB[p * COUT_REAL + oct * 16 + fq * 4]) = sv;
        } else if (OMODE == 2) {
            size_t p = (size_t)b * HW_ + (size_t)(y0 + py) * W_ + x0 + fr;
            float4 o4;
            #pragma unroll
            for (int j = 0; j < 4; ++j) {
                int oc = oct * 16 + fq * 4 + j;
                float v = acc[i][0][j] + (oc < COUT_REAL ? bias[oc] : 0.f);
                ((float*)&o4)[j] = v;
            }
            *reinterpret_cast<float4*>(&outF[p * 32 + oct * 16 + fq * 4]) = o4;
        } else {
            #pragma unroll
            for (int j = 0; j < 4; ++j) {
                int oc = oct * 16 + fq * 4 + j;
                if (oc >= COUT_REAL) continue;
                size_t off = ((size_t)b * COUT_REAL + oc) * HW_
                           + (size_t)(y0 + py) * W_ + x0 + fr;
                float v = acc[i][0][j] + bias[oc];
                if (DUAL) {
                    float be = acc[i][1][j] + bias2[oc];
                    float nv = nrm[off];
                    outF[off] = fmaf(nv, 1.f + v, be);
                } else {
                    outF[off] = RELU ? fmaxf(v, 0.f) : v;
                }
            }
        }
    }
}

// ---------------------------------------------------------------------------
// DCNv2 fused. Block = 16 px, 256 thr.
// phase0: om px-major [p][32] -> corner weights/indices (line-local reads)
// phase1: gather bf16 ref channels from cc[p][64..128); ushort4 loads
// phase2: MFMA matvec; bf16 [p][64] output
// ---------------------------------------------------------------------------
constexpr int SROW = 584;

__global__ __launch_bounds__(256)
void dcn_kernel(const unsigned short* __restrict__ cc, const float* __restrict__ omP,
                const unsigned short* __restrict__ wbd, const float* __restrict__ b_dcn,
                unsigned short* __restrict__ rrT) {
    __shared__ unsigned short sS[16 * SROW];
    __shared__ float4 cwL[144];
    __shared__ int4   ciL[144];

    int t  = threadIdx.x;
    int b  = blockIdx.x / 576;
    int p0 = (blockIdx.x % 576) * 16;

    const unsigned short* ccb = cc + (size_t)b * HW_ * 128;

    // ---- phase 0: corner weights/indices ----
    if (t < 144) {
        int pp = t / 9, k = t - pp * 9;
        int p  = p0 + pp;
        int y  = p / W_, x = p - y * W_;
        const float* omp = &omP[(size_t)(b * HW_ + p) * 32];
        float dy = omp[2 * k];
        float dx = omp[2 * k + 1];
        float mk = omp[18 + k];
        mk = 1.f / (1.f + expf(-mk));

        float py = dy + (float)y + (float)(k / 3 - 1);
        float px = dx + (float)x + (float)(k % 3 - 1);
        float fy = floorf(py), fx = floorf(px);
        int   y0 = (int)fy,   x0 = (int)fx;
        float wy = py - fy,   wx = px - fx;

        float cw[4];
        int   ci[4];
        #pragma unroll
        for (int i = 0; i < 4; ++i) {
            int yy = y0 + (i >> 1);
            int xx = x0 + (i & 1);
            bool valid = (yy >= 0) && (yy < H_) && (xx >= 0) && (xx < W_);
            int yc = yy < 0 ? 0 : (yy > H_ - 1 ? H_ - 1 : yy);
            int xc = xx < 0 ? 0 : (xx > W_ - 1 ? W_ - 1 : xx);
            ci[i] = yc * W_ + xc;
            float wyi = (i >> 1) ? wy : (1.f - wy);
            float wxi = (i & 1)  ? wx : (1.f - wx);
            cw[i] = valid ? mk * wyi * wxi : 0.f;
        }
        cwL[t] = make_float4(cw[0], cw[1], cw[2], cw[3]);
        ciL[t] = make_int4(ci[0], ci[1], ci[2], ci[3]);
    }
    __syncthreads();

    // ---- phase 1: bf16 gather from cc ----
    {
        int pp = t >> 4, cg = t & 15;
        #pragma unroll
        for (int k = 0; k < 9; ++k) {
            float4 cw = cwL[pp * 9 + k];
            int4   ci = ciL[pp * 9 + k];
            ushort4 r0 = *reinterpret_cast<const ushort4*>(&ccb[(size_t)ci.x * 128 + 64 + cg * 4]);
            ushort4 r1 = *reinterpret_cast<const ushort4*>(&ccb[(size_t)ci.y * 128 + 64 + cg * 4]);
            ushort4 r2 = *reinterpret_cast<const ushort4*>(&ccb[(size_t)ci.z * 128 + 64 + cg * 4]);
            ushort4 r3 = *reinterpret_cast<const ushort4*>(&ccb[(size_t)ci.w * 128 + 64 + cg * 4]);
            float vx = cw.x * bf2f(r0.x) + cw.y * bf2f(r1.x) + cw.z * bf2f(r2.x) + cw.w * bf2f(r3.x);
            float vy = cw.x * bf2f(r0.y) + cw.y * bf2f(r1.y) + cw.z * bf2f(r2.y) + cw.w * bf2f(r3.y);
            float vz = cw.x * bf2f(r0.z) + cw.y * bf2f(r1.z) + cw.z * bf2f(r2.z) + cw.w * bf2f(r3.z);
            float vw = cw.x * bf2f(r0.w) + cw.y * bf2f(r1.w) + cw.z * bf2f(r2.w) + cw.w * bf2f(r3.w);
            ushort4 sv;
            sv.x = f2bf(vx); sv.y = f2bf(vy); sv.z = f2bf(vz); sv.w = f2bf(vw);
            *reinterpret_cast<ushort4*>(&sS[pp * SROW + k * 64 + cg * 4]) = sv;
        }
    }
    __syncthreads();

    // ---- phase 2: MFMA matvec ----
    int wave = t >> 6, lane = t & 63;
    int fr = lane & 15, fq = lane >> 4;

    f32x4 acc = (f32x4){0.f, 0.f, 0.f, 0.f};
    for (int ks = 0; ks < 18; ++ks) {
        bf16x8 wf = ld_frag(&wbd[(size_t)(wave * 16 + fr) * 576 + ks * 32 + fq * 8]);
        bf16x8 pf = ld_frag(&sS[(size_t)fr * SROW + ks * 32 + fq * 8]);
        acc = __builtin_amdgcn_mfma_f32_16x16x32_bf16(wf, pf, acc, 0, 0, 0);
    }

    {
        size_t p = (size_t)b * HW_ + p0 + fr;
        ushort4 sv;
        #pragma unroll
        for (int j = 0; j < 4; ++j)
            ((unsigned short*)&sv)[j] = f2bf(acc[j] + b_dcn[wave * 16 + fq * 4 + j]);
        *reinterpret_cast<ushort4*>(&rrT[p * 64 + wave * 16 + fq * 4]) = sv;
    }
}

} // namespace

// ---------------------------------------------------------------------------
extern "C" void kernel_launch(void* const* d_in, const int* in_sizes, int n_in,
                              void* d_out, int out_size, void* d_ws, size_t ws_size,
                              hipStream_t stream) {
    (void)in_sizes; (void)n_in; (void)out_size; (void)ws_size;

    const float* x     = (const float*)d_in[0];
    const float* ref   = (const float*)d_in[1];
    const float* w1    = (const float*)d_in[2];
    const float* b1    = (const float*)d_in[3];
    const float* w2    = (const float*)d_in[4];
    const float* b2    = (const float*)d_in[5];
    const float* w_off = (const float*)d_in[6];
    const float* b_off = (const float*)d_in[7];
    const float* w_dcn = (const float*)d_in[8];
    const float* b_dcn = (const float*)d_in[9];
    const float* w_g   = (const float*)d_in[10];
    const float* b_g   = (const float*)d_in[11];
    const float* w_be  = (const float*)d_in[12];
    const float* b_be  = (const float*)d_in[13];

    float* out = (float*)d_out;
    float* ws  = (float*)d_ws;

    // f32 buffers
    float* nrm = ws;                        // 1,179,648 f   [b][c][p]
    float* omP = nrm + 1179648;             //   589,824 f   [b][p][32]
    // bf16 buffers
    unsigned short* cc    = (unsigned short*)(omP + 589824); // [b][p][128]  2,359,296
    unsigned short* hmidT = cc    + 2359296;                 // [b][p][16]     294,912
    unsigned short* condT = hmidT + 294912;                  // [b][p][64]   1,179,648
    unsigned short* rrT   = condT + 1179648;                 // [b][p][64]   1,179,648
    // weights
    unsigned short* wt1   = rrT   + 1179648;                 // 18,432
    unsigned short* wt2   = wt1   + 18432;                   // 18,432
    unsigned short* wtoff = wt2   + 18432;                   // 18,432
    unsigned short* wtg   = wtoff + 18432;                   // 36,864
    unsigned short* wtbe  = wtg   + 36864;                   // 36,864
    unsigned short* wbd   = wtbe  + 36864;                   // 36,864

    prologue<<<432, 256, 0, stream>>>(x, ref, w1, w2, w_off, w_g, w_be, w_dcn,
                                      nrm, cc, wt1, wt2, wtoff, wtg, wtbe, wbd);

    constexpr int GRID = 288;

    // conv1: cc[p][128] -> hmidT[p][16], ReLU
    conv_bf<128, 128, 136, 16, 16, false, true, 1>
        <<<GRID, 256, 0, stream>>>(cc, wt1, nullptr, b1, nullptr, nullptr, nullptr, hmidT);

    // conv2: hmidT[p][16] -> condT[p][64], ReLU (ICP=32, upper 16 zero)
    conv_bf<16, 32, 40, 64, 64, false, true, 1>
        <<<GRID, 256, 0, stream>>>(hmidT, wt2, nullptr, b2, nullptr, nullptr, nullptr, condT);

    // conv_off: condT[p][64] -> omP f32 [p][32] px-major
    conv_bf<64, 64, 72, 32, 27, false, false, 2>
        <<<GRID, 256, 0, stream>>>(condT, wtoff, nullptr, b_off, nullptr, nullptr, omP, nullptr);

    dcn_kernel<<<B_ * 576, 256, 0, stream>>>(cc, omP, wbd, b_dcn, rrT);

    // final: rrT[p][64] -> out f32 [64][p], gamma/beta DUAL + affine epilogue
    conv_bf<64, 64, 72, 64, 64, true, false, 0>
        <<<GRID, 256, 0, stream>>>(rrT, wtg, wtbe, b_g, b_be, nrm, out, nullptr);
}

// Round 9
// 68.444 us; speedup vs baseline: 5.0974x; 1.0777x over previous
//
#include <hip/hip_runtime.h>
#include <math.h>

namespace {

typedef __attribute__((ext_vector_type(8))) short          bf16x8;
typedef __attribute__((ext_vector_type(8))) unsigned short u16x8;
typedef __attribute__((ext_vector_type(4))) float          f32x4;

constexpr int B_  = 2;
constexpr int H_  = 96;
constexpr int W_  = 96;
constexpr int HW_ = H_ * W_;
constexpr int NC_ = 64;
constexpr int SC_ = 64;

__device__ inline unsigned short f2bf(float f) {
    union { float f; unsigned u; } v; v.f = f;
    unsigned r = v.u + 0x7FFFu + ((v.u >> 16) & 1u);
    return (unsigned short)(r >> 16);
}
__device__ inline float bf2f(unsigned short s) {
    union { unsigned u; float f; } v; v.u = ((unsigned)s) << 16; return v.f;
}
__device__ inline bf16x8 ld_frag(const unsigned short* p) {
    return *reinterpret_cast<const bf16x8*>(p);
}

// ---------------------------------------------------------------------------
// prologue (grid 432): blocks 0..287 norm + ref transpose; 288..431 weights.
// (unchanged from round 8)
// ---------------------------------------------------------------------------
__global__ __launch_bounds__(256)
void prologue(const float* __restrict__ x, const float* __restrict__ ref,
              const float* __restrict__ w1, const float* __restrict__ w2,
              const float* __restrict__ woff, const float* __restrict__ wg,
              const float* __restrict__ wbe, const float* __restrict__ wdcn,
              float* __restrict__ nrm, unsigned short* __restrict__ cc,
              unsigned short* __restrict__ wt1, unsigned short* __restrict__ wt2,
              unsigned short* __restrict__ wtoff, unsigned short* __restrict__ wtg,
              unsigned short* __restrict__ wtbe, unsigned short* __restrict__ wbd) {
    __shared__ float red1[4][64];
    __shared__ float red2[4][64];
    __shared__ float rtile[64][65];

    int blk = blockIdx.x;
    int t   = threadIdx.x;

    if (blk < 288) {
        int b  = blk / 144;
        int p0 = (blk % 144) * 64;
        int px = t & 63;
        int cg = t >> 6;
        int p  = p0 + px;

        float v[16];
        float s1 = 0.f, s2 = 0.f;
        const float* xb = x + ((size_t)b * NC_ + cg * 16) * HW_ + p;
        #pragma unroll
        for (int j = 0; j < 16; ++j) {
            v[j] = xb[j * HW_];
            s1 += v[j];
            s2 = fmaf(v[j], v[j], s2);
        }
        red1[cg][px] = s1;
        red2[cg][px] = s2;

        const float* rb = ref + (size_t)b * SC_ * HW_ + p0 + px;
        #pragma unroll
        for (int it = 0; it < 16; ++it) {
            int ch = it * 4 + cg;
            rtile[ch][px] = rb[(size_t)ch * HW_];
        }
        __syncthreads();

        s1 = red1[0][px] + red1[1][px] + red1[2][px] + red1[3][px];
        s2 = red2[0][px] + red2[1][px] + red2[2][px] + red2[3][px];
        float mean = s1 * (1.f / 64.f);
        float var  = (s2 - 64.f * mean * mean) * (1.f / 63.f);
        float inv  = 1.f / sqrtf(var + 1e-5f);
        float* nb = nrm + ((size_t)b * NC_ + cg * 16) * HW_ + p;
        u16x8 pk[2];
        #pragma unroll
        for (int j = 0; j < 16; ++j) {
            float nv = (v[j] - mean) * inv;
            nb[j * HW_] = nv;
            pk[j >> 3][j & 7] = f2bf(nv);
        }
        size_t bp = (size_t)b * HW_ + p;
        *reinterpret_cast<u16x8*>(&cc[bp * 128 + cg * 16 + 0]) = pk[0];
        *reinterpret_cast<u16x8*>(&cc[bp * 128 + cg * 16 + 8]) = pk[1];

        {
            int wpx = t >> 2, q = t & 3;
            size_t bp2 = (size_t)b * HW_ + p0 + wpx;
            u16x8 o0, o1;
            #pragma unroll
            for (int j = 0; j < 8; ++j) {
                o0[j] = f2bf(rtile[q * 16 + j][wpx]);
                o1[j] = f2bf(rtile[q * 16 + 8 + j][wpx]);
            }
            *reinterpret_cast<u16x8*>(&cc[bp2 * 128 + 64 + q * 16 + 0]) = o0;
            *reinterpret_cast<u16x8*>(&cc[bp2 * 128 + 64 + q * 16 + 8]) = o1;
        }
    } else {
        int idx = (blk - 288) * 256 + t;
        if (idx < 9 * 16 * 128) {
            int tap = idx / (16 * 128), oc = (idx / 128) % 16, ic = idx % 128;
            wt1[idx] = f2bf(w1[(oc * 128 + ic) * 9 + tap]);
        }
        if (idx < 9 * 64 * 32) {
            int tap = idx / (64 * 32), oc = (idx / 32) % 64, ic = idx % 32;
            wt2[idx] = (ic < 16) ? f2bf(w2[(oc * 16 + ic) * 9 + tap]) : (unsigned short)0;
        }
        if (idx < 9 * 32 * 64) {
            int tap = idx / (32 * 64), oc = (idx / 64) % 32, ic = idx % 64;
            wtoff[idx] = (oc < 27) ? f2bf(woff[(oc * 64 + ic) * 9 + tap]) : (unsigned short)0;
        }
        if (idx < 9 * 64 * 64) {
            int tap = idx / (64 * 64), oc = (idx / 64) % 64, ic = idx % 64;
            wtg[idx]  = f2bf(wg [(oc * 64 + ic) * 9 + tap]);
            wtbe[idx] = f2bf(wbe[(oc * 64 + ic) * 9 + tap]);
        }
        if (idx < 64 * 576) {
            int oc = idx / 576, r = idx - oc * 576;
            int tap = r >> 6, ic = r & 63;
            wbd[idx] = f2bf(wdcn[oc * 576 + ic * 9 + tap]);
        }
    }
}

// ---------------------------------------------------------------------------
// Tap-decomposed MFMA conv 3x3 (unchanged from round 8)
// ---------------------------------------------------------------------------
template <int ICS, int ICP, int COLP, int COUT_PAD, int COUT_REAL,
          bool DUAL, bool RELU, int OMODE>
__global__ __launch_bounds__(256)
void conv_bf(const unsigned short* __restrict__ in,
             const unsigned short* __restrict__ Wt,
             const unsigned short* __restrict__ Wt2,
             const float* __restrict__ bias, const float* __restrict__ bias2,
             const float* __restrict__ nrm, float* __restrict__ outF,
             unsigned short* __restrict__ outB) {
    constexpr int NOCT = COUT_PAD / 16;
    constexpr int WPO  = 4 / NOCT;
    constexpr int MTP  = NOCT;
    constexpr int NACC = DUAL ? 2 : 1;
    constexpr int NKS  = ICP / 32;
    constexpr int NCH8 = ICP / 8;

    __shared__ unsigned short patch[6 * 18 * COLP];

    int t   = threadIdx.x;
    int blk = blockIdx.x;
    int bx  = blk % 6;
    int by  = (blk / 6) % 24;
    int b   = blk / 144;
    int x0  = bx * 16, y0 = by * 4;

    for (int e = t; e < 6 * 18 * NCH8; e += 256) {
        int kc  = e % NCH8;
        int col = (e / NCH8) % 18;
        int row = e / (NCH8 * 18);
        int yy = y0 + row - 1, xx = x0 + col - 1;
        bf16x8 v = (bf16x8){0, 0, 0, 0, 0, 0, 0, 0};
        if (kc * 8 < ICS && (unsigned)yy < (unsigned)H_ && (unsigned)xx < (unsigned)W_) {
            v = ld_frag(&in[((size_t)b * HW_ + yy * W_ + xx) * ICS + kc * 8]);
        }
        *reinterpret_cast<bf16x8*>(&patch[(row * 18 + col) * COLP + kc * 8]) = v;
    }
    __syncthreads();

    int wave = t >> 6, lane = t & 63;
    int fr = lane & 15, fq = lane >> 4;
    int oct  = wave / WPO;
    int widx = wave - oct * WPO;
    int mt0  = widx * MTP;

    f32x4 acc[MTP][NACC];
    #pragma unroll
    for (int i = 0; i < MTP; ++i)
        #pragma unroll
        for (int a = 0; a < NACC; ++a)
            acc[i][a] = (f32x4){0.f, 0.f, 0.f, 0.f};

    constexpr int dyv[9] = {0,0,0,1,1,1,2,2,2};
    constexpr int dxv[9] = {0,1,2,0,1,2,0,1,2};

    #pragma unroll
    for (int tap = 0; tap < 9; ++tap) {
        int dy = dyv[tap], dx = dxv[tap];
        #pragma unroll
        for (int ks = 0; ks < NKS; ++ks) {
            const size_t wo = ((size_t)tap * COUT_PAD + oct * 16 + fr) * ICP + ks * 32 + fq * 8;
            bf16x8 wfA = ld_frag(&Wt[wo]);
            bf16x8 wfB;
            if (DUAL) wfB = ld_frag(&Wt2[wo]);
            #pragma unroll
            for (int i = 0; i < MTP; ++i) {
                bf16x8 pf = ld_frag(&patch[((mt0 + i + dy) * 18 + (fr + dx)) * COLP
                                           + ks * 32 + fq * 8]);
                acc[i][0] = __builtin_amdgcn_mfma_f32_16x16x32_bf16(wfA, pf, acc[i][0], 0, 0, 0);
                if (DUAL)
                    acc[i][1] = __builtin_amdgcn_mfma_f32_16x16x32_bf16(wfB, pf, acc[i][1], 0, 0, 0);
            }
        }
    }

    #pragma unroll
    for (int i = 0; i < MTP; ++i) {
        int py = mt0 + i;
        if (OMODE == 1) {
            size_t p = (size_t)b * HW_ + (size_t)(y0 + py) * W_ + x0 + fr;
            ushort4 sv;
            #pragma unroll
            for (int j = 0; j < 4; ++j) {
                float v = acc[i][0][j] + bias[oct * 16 + fq * 4 + j];
                if (RELU) v = fmaxf(v, 0.f);
                ((unsigned short*)&sv)[j] = f2bf(v);
            }
            *reinterpret_cast<ushort4*>(&outB[p * COUT_REAL + oct * 16 + fq * 4]) = sv;
        } else if (OMODE == 2) {
            size_t p = (size_t)b * HW_ + (size_t)(y0 + py) * W_ + x0 + fr;
            float4 o4;
            #pragma unroll
            for (int j = 0; j < 4; ++j) {
                int oc = oct * 16 + fq * 4 + j;
                float v = acc[i][0][j] + (oc < COUT_REAL ? bias[oc] : 0.f);
                ((float*)&o4)[j] = v;
            }
            *reinterpret_cast<float4*>(&outF[p * 32 + oct * 16 + fq * 4]) = o4;
        } else {
            #pragma unroll
            for (int j = 0; j < 4; ++j) {
                int oc = oct * 16 + fq * 4 + j;
                if (oc >= COUT_REAL) continue;
                size_t off = ((size_t)b * COUT_REAL + oc) * HW_
                           + (size_t)(y0 + py) * W_ + x0 + fr;
                float v = acc[i][0][j] + bias[oc];
                if (DUAL) {
                    float be = acc[i][1][j] + bias2[oc];
                    float nv = nrm[off];
                    outF[off] = fmaf(nv, 1.f + v, be);
                } else {
                    outF[off] = RELU ? fmaxf(v, 0.f) : v;
                }
            }
        }
    }
}

// ---------------------------------------------------------------------------
// DCNv2 fused, DTILE=32. Block = 32 px, 256 thr, XCD-swizzled grid (576).
// phase0: 288 (pp,k) pairs over all threads -> corner weights/indices
// phase1: (pp = t>>3, cg8 = t&7): per tap, 4 corner u16x8 (16B) gathers,
//         8 channels -> bf16 sS[pp][k*64 + cg8*8]
// phase2: wave = oc-tile; 18 ks x (1 wf + 2 pf + 2 mfma); wf reused.
// ---------------------------------------------------------------------------
constexpr int SROW = 584;
constexpr int DT   = 32;

__global__ __launch_bounds__(256)
void dcn_kernel(const unsigned short* __restrict__ cc, const float* __restrict__ omP,
                const unsigned short* __restrict__ wbd, const float* __restrict__ b_dcn,
                unsigned short* __restrict__ rrT) {
    __shared__ unsigned short sS[DT * SROW];   // 36.5 KiB
    __shared__ float4 cwL[DT * 9];
    __shared__ int4   ciL[DT * 9];

    int t = threadIdx.x;
    // bijective XCD swizzle: nwg = 576, q = 72
    int bid = blockIdx.x;
    int swz = (bid & 7) * 72 + (bid >> 3);
    int b   = swz / (HW_ / DT);
    int p0  = (swz % (HW_ / DT)) * DT;

    const unsigned short* ccb = cc + (size_t)b * HW_ * 128;

    // ---- phase 0 ----
    for (int e = t; e < DT * 9; e += 256) {
        int pp = e / 9, k = e - pp * 9;
        int p  = p0 + pp;
        int y  = p / W_, x = p - y * W_;
        const float* omp = &omP[(size_t)(b * HW_ + p) * 32];
        float dy = omp[2 * k];
        float dx = omp[2 * k + 1];
        float mk = omp[18 + k];
        mk = 1.f / (1.f + expf(-mk));

        float py = dy + (float)y + (float)(k / 3 - 1);
        float px = dx + (float)x + (float)(k % 3 - 1);
        float fy = floorf(py), fx = floorf(px);
        int   y0 = (int)fy,   x0 = (int)fx;
        float wy = py - fy,   wx = px - fx;

        float cw[4];
        int   ci[4];
        #pragma unroll
        for (int i = 0; i < 4; ++i) {
            int yy = y0 + (i >> 1);
            int xx = x0 + (i & 1);
            bool valid = (yy >= 0) && (yy < H_) && (xx >= 0) && (xx < W_);
            int yc = yy < 0 ? 0 : (yy > H_ - 1 ? H_ - 1 : yy);
            int xc = xx < 0 ? 0 : (xx > W_ - 1 ? W_ - 1 : xx);
            ci[i] = yc * W_ + xc;
            float wyi = (i >> 1) ? wy : (1.f - wy);
            float wxi = (i & 1)  ? wx : (1.f - wx);
            cw[i] = valid ? mk * wyi * wxi : 0.f;
        }
        cwL[e] = make_float4(cw[0], cw[1], cw[2], cw[3]);
        ciL[e] = make_int4(ci[0], ci[1], ci[2], ci[3]);
    }
    __syncthreads();

    // ---- phase 1: bf16 gather, 8 ch per thread, 16B loads ----
    {
        int pp = t >> 3, cg8 = t & 7;
        #pragma unroll
        for (int k = 0; k < 9; ++k) {
            float4 cw = cwL[pp * 9 + k];
            int4   ci = ciL[pp * 9 + k];
            u16x8 r0 = *reinterpret_cast<const u16x8*>(&ccb[(size_t)ci.x * 128 + 64 + cg8 * 8]);
            u16x8 r1 = *reinterpret_cast<const u16x8*>(&ccb[(size_t)ci.y * 128 + 64 + cg8 * 8]);
            u16x8 r2 = *reinterpret_cast<const u16x8*>(&ccb[(size_t)ci.z * 128 + 64 + cg8 * 8]);
            u16x8 r3 = *reinterpret_cast<const u16x8*>(&ccb[(size_t)ci.w * 128 + 64 + cg8 * 8]);
            u16x8 sv;
            #pragma unroll
            for (int j = 0; j < 8; ++j) {
                float v = cw.x * bf2f(r0[j]) + cw.y * bf2f(r1[j])
                        + cw.z * bf2f(r2[j]) + cw.w * bf2f(r3[j]);
                sv[j] = f2bf(v);
            }
            *reinterpret_cast<u16x8*>(&sS[pp * SROW + k * 64 + cg8 * 8]) = sv;
        }
    }
    __syncthreads();

    // ---- phase 2: MFMA matvec, 2 m-tiles per wave ----
    int wave = t >> 6, lane = t & 63;
    int fr = lane & 15, fq = lane >> 4;

    f32x4 acc0 = (f32x4){0.f, 0.f, 0.f, 0.f};
    f32x4 acc1 = (f32x4){0.f, 0.f, 0.f, 0.f};
    for (int ks = 0; ks < 18; ++ks) {
        bf16x8 wf  = ld_frag(&wbd[(size_t)(wave * 16 + fr) * 576 + ks * 32 + fq * 8]);
        bf16x8 pf0 = ld_frag(&sS[(size_t)fr * SROW + ks * 32 + fq * 8]);
        bf16x8 pf1 = ld_frag(&sS[(size_t)(16 + fr) * SROW + ks * 32 + fq * 8]);
        acc0 = __builtin_amdgcn_mfma_f32_16x16x32_bf16(wf, pf0, acc0, 0, 0, 0);
        acc1 = __builtin_amdgcn_mfma_f32_16x16x32_bf16(wf, pf1, acc1, 0, 0, 0);
    }

    {
        size_t p = (size_t)b * HW_ + p0 + fr;
        ushort4 sv0, sv1;
        #pragma unroll
        for (int j = 0; j < 4; ++j) {
            float bo = b_dcn[wave * 16 + fq * 4 + j];
            ((unsigned short*)&sv0)[j] = f2bf(acc0[j] + bo);
            ((unsigned short*)&sv1)[j] = f2bf(acc1[j] + bo);
        }
        *reinterpret_cast<ushort4*>(&rrT[p * 64 + wave * 16 + fq * 4]) = sv0;
        *reinterpret_cast<ushort4*>(&rrT[(p + 16) * 64 + wave * 16 + fq * 4]) = sv1;
    }
}

} // namespace

// ---------------------------------------------------------------------------
extern "C" void kernel_launch(void* const* d_in, const int* in_sizes, int n_in,
                              void* d_out, int out_size, void* d_ws, size_t ws_size,
                              hipStream_t stream) {
    (void)in_sizes; (void)n_in; (void)out_size; (void)ws_size;

    const float* x     = (const float*)d_in[0];
    const float* ref   = (const float*)d_in[1];
    const float* w1    = (const float*)d_in[2];
    const float* b1    = (const float*)d_in[3];
    const float* w2    = (const float*)d_in[4];
    const float* b2    = (const float*)d_in[5];
    const float* w_off = (const float*)d_in[6];
    const float* b_off = (const float*)d_in[7];
    const float* w_dcn = (const float*)d_in[8];
    const float* b_dcn = (const float*)d_in[9];
    const float* w_g   = (const float*)d_in[10];
    const float* b_g   = (const float*)d_in[11];
    const float* w_be  = (const float*)d_in[12];
    const float* b_be  = (const float*)d_in[13];

    float* out = (float*)d_out;
    float* ws  = (float*)d_ws;

    float* nrm = ws;                        // 1,179,648 f   [b][c][p]
    float* omP = nrm + 1179648;             //   589,824 f   [b][p][32]
    unsigned short* cc    = (unsigned short*)(omP + 589824); // [b][p][128]
    unsigned short* hmidT = cc    + 2359296;                 // [b][p][16]
    unsigned short* condT = hmidT + 294912;                  // [b][p][64]
    unsigned short* rrT   = condT + 1179648;                 // [b][p][64]
    unsigned short* wt1   = rrT   + 1179648;
    unsigned short* wt2   = wt1   + 18432;
    unsigned short* wtoff = wt2   + 18432;
    unsigned short* wtg   = wtoff + 18432;
    unsigned short* wtbe  = wtg   + 36864;
    unsigned short* wbd   = wtbe  + 36864;

    prologue<<<432, 256, 0, stream>>>(x, ref, w1, w2, w_off, w_g, w_be, w_dcn,
                                      nrm, cc, wt1, wt2, wtoff, wtg, wtbe, wbd);

    constexpr int GRID = 288;

    conv_bf<128, 128, 136, 16, 16, false, true, 1>
        <<<GRID, 256, 0, stream>>>(cc, wt1, nullptr, b1, nullptr, nullptr, nullptr, hmidT);

    conv_bf<16, 32, 40, 64, 64, false, true, 1>
        <<<GRID, 256, 0, stream>>>(hmidT, wt2, nullptr, b2, nullptr, nullptr, nullptr, condT);

    conv_bf<64, 64, 72, 32, 27, false, false, 2>
        <<<GRID, 256, 0, stream>>>(condT, wtoff, nullptr, b_off, nullptr, nullptr, omP, nullptr);

    dcn_kernel<<<B_ * (HW_ / DT), 256, 0, stream>>>(cc, omP, wbd, b_dcn, rrT);

    conv_bf<64, 64, 72, 64, 64, true, false, 0>
        <<<GRID, 256, 0, stream>>>(rrT, wtg, wtbe, b_g, b_be, nrm, out, nullptr);
}

// Round 10
// 68.016 us; speedup vs baseline: 5.1295x; 1.0063x over previous
//
#include <hip/hip_runtime.h>
#include <math.h>

namespace {

typedef __attribute__((ext_vector_type(8))) short          bf16x8;
typedef __attribute__((ext_vector_type(8))) unsigned short u16x8;
typedef __attribute__((ext_vector_type(8))) _Float16       f16x8;
typedef __attribute__((ext_vector_type(4))) float          f32x4;

constexpr int B_  = 2;
constexpr int H_  = 96;
constexpr int W_  = 96;
constexpr int HW_ = H_ * W_;
constexpr int NC_ = 64;
constexpr int SC_ = 64;

__device__ inline unsigned short f2bf(float f) {
    union { float f; unsigned u; } v; v.f = f;
    unsigned r = v.u + 0x7FFFu + ((v.u >> 16) & 1u);
    return (unsigned short)(r >> 16);
}
__device__ inline unsigned short f2hbits(float f) {
    union { _Float16 h; unsigned short u; } s; s.h = (_Float16)f; return s.u;
}
__device__ inline _Float16 hfrombits(unsigned short u) {
    union { _Float16 h; unsigned short u; } s; s.u = u; return s.h;
}
__device__ inline bf16x8 ld_frag(const unsigned short* p) {
    return *reinterpret_cast<const bf16x8*>(p);
}

// ---------------------------------------------------------------------------
// prologue (grid 432): blocks 0..287 norm + ref transpose (cc bf16 + ccH f16);
// blocks 288..431 weight prep.
// ---------------------------------------------------------------------------
__global__ __launch_bounds__(256)
void prologue(const float* __restrict__ x, const float* __restrict__ ref,
              const float* __restrict__ w1, const float* __restrict__ w2,
              const float* __restrict__ woff, const float* __restrict__ wg,
              const float* __restrict__ wbe, const float* __restrict__ wdcn,
              float* __restrict__ nrm, unsigned short* __restrict__ cc,
              unsigned short* __restrict__ ccH,
              unsigned short* __restrict__ wt1, unsigned short* __restrict__ wt2,
              unsigned short* __restrict__ wtoff, unsigned short* __restrict__ wtg,
              unsigned short* __restrict__ wtbe, unsigned short* __restrict__ wbdH) {
    __shared__ float red1[4][64];
    __shared__ float red2[4][64];
    __shared__ float rtile[64][65];

    int blk = blockIdx.x;
    int t   = threadIdx.x;

    if (blk < 288) {
        int b  = blk / 144;
        int p0 = (blk % 144) * 64;
        int px = t & 63;
        int cg = t >> 6;
        int p  = p0 + px;

        float v[16];
        float s1 = 0.f, s2 = 0.f;
        const float* xb = x + ((size_t)b * NC_ + cg * 16) * HW_ + p;
        #pragma unroll
        for (int j = 0; j < 16; ++j) {
            v[j] = xb[j * HW_];
            s1 += v[j];
            s2 = fmaf(v[j], v[j], s2);
        }
        red1[cg][px] = s1;
        red2[cg][px] = s2;

        const float* rb = ref + (size_t)b * SC_ * HW_ + p0 + px;
        #pragma unroll
        for (int it = 0; it < 16; ++it) {
            int ch = it * 4 + cg;
            rtile[ch][px] = rb[(size_t)ch * HW_];
        }
        __syncthreads();

        s1 = red1[0][px] + red1[1][px] + red1[2][px] + red1[3][px];
        s2 = red2[0][px] + red2[1][px] + red2[2][px] + red2[3][px];
        float mean = s1 * (1.f / 64.f);
        float var  = (s2 - 64.f * mean * mean) * (1.f / 63.f);
        float inv  = 1.f / sqrtf(var + 1e-5f);
        float* nb = nrm + ((size_t)b * NC_ + cg * 16) * HW_ + p;
        u16x8 pk[2];
        #pragma unroll
        for (int j = 0; j < 16; ++j) {
            float nv = (v[j] - mean) * inv;
            nb[j * HW_] = nv;
            pk[j >> 3][j & 7] = f2bf(nv);
        }
        size_t bp = (size_t)b * HW_ + p;
        *reinterpret_cast<u16x8*>(&cc[bp * 128 + cg * 16 + 0]) = pk[0];
        *reinterpret_cast<u16x8*>(&cc[bp * 128 + cg * 16 + 8]) = pk[1];

        {
            int wpx = t >> 2, q = t & 3;
            size_t bp2 = (size_t)b * HW_ + p0 + wpx;
            u16x8 o0, o1, h0, h1;
            #pragma unroll
            for (int j = 0; j < 8; ++j) {
                float v0 = rtile[q * 16 + j][wpx];
                float v1 = rtile[q * 16 + 8 + j][wpx];
                o0[j] = f2bf(v0);    o1[j] = f2bf(v1);
                h0[j] = f2hbits(v0); h1[j] = f2hbits(v1);
            }
            *reinterpret_cast<u16x8*>(&cc[bp2 * 128 + 64 + q * 16 + 0]) = o0;
            *reinterpret_cast<u16x8*>(&cc[bp2 * 128 + 64 + q * 16 + 8]) = o1;
            *reinterpret_cast<u16x8*>(&ccH[bp2 * 64 + q * 16 + 0]) = h0;
            *reinterpret_cast<u16x8*>(&ccH[bp2 * 64 + q * 16 + 8]) = h1;
        }
    } else {
        int idx = (blk - 288) * 256 + t;
        if (idx < 9 * 16 * 128) {
            int tap = idx / (16 * 128), oc = (idx / 128) % 16, ic = idx % 128;
            wt1[idx] = f2bf(w1[(oc * 128 + ic) * 9 + tap]);
        }
        if (idx < 9 * 64 * 32) {
            int tap = idx / (64 * 32), oc = (idx / 32) % 64, ic = idx % 32;
            wt2[idx] = (ic < 16) ? f2bf(w2[(oc * 16 + ic) * 9 + tap]) : (unsigned short)0;
        }
        if (idx < 9 * 32 * 64) {
            int tap = idx / (32 * 64), oc = (idx / 64) % 32, ic = idx % 64;
            wtoff[idx] = (oc < 27) ? f2bf(woff[(oc * 64 + ic) * 9 + tap]) : (unsigned short)0;
        }
        if (idx < 9 * 64 * 64) {
            int tap = idx / (64 * 64), oc = (idx / 64) % 64, ic = idx % 64;
            wtg[idx]  = f2bf(wg [(oc * 64 + ic) * 9 + tap]);
            wtbe[idx] = f2bf(wbe[(oc * 64 + ic) * 9 + tap]);
        }
        if (idx < 64 * 576) {
            int oc = idx / 576, r = idx - oc * 576;
            int tap = r >> 6, ic = r & 63;
            wbdH[idx] = f2hbits(wdcn[oc * 576 + ic * 9 + tap]);
        }
    }
}

// ---------------------------------------------------------------------------
// Tap-decomposed MFMA conv 3x3 (unchanged from round 9)
// ---------------------------------------------------------------------------
template <int ICS, int ICP, int COLP, int COUT_PAD, int COUT_REAL,
          bool DUAL, bool RELU, int OMODE>
__global__ __launch_bounds__(256)
void conv_bf(const unsigned short* __restrict__ in,
             const unsigned short* __restrict__ Wt,
             const unsigned short* __restrict__ Wt2,
             const float* __restrict__ bias, const float* __restrict__ bias2,
             const float* __restrict__ nrm, float* __restrict__ outF,
             unsigned short* __restrict__ outB) {
    constexpr int NOCT = COUT_PAD / 16;
    constexpr int WPO  = 4 / NOCT;
    constexpr int MTP  = NOCT;
    constexpr int NACC = DUAL ? 2 : 1;
    constexpr int NKS  = ICP / 32;
    constexpr int NCH8 = ICP / 8;

    __shared__ unsigned short patch[6 * 18 * COLP];

    int t   = threadIdx.x;
    int blk = blockIdx.x;
    int bx  = blk % 6;
    int by  = (blk / 6) % 24;
    int b   = blk / 144;
    int x0  = bx * 16, y0 = by * 4;

    for (int e = t; e < 6 * 18 * NCH8; e += 256) {
        int kc  = e % NCH8;
        int col = (e / NCH8) % 18;
        int row = e / (NCH8 * 18);
        int yy = y0 + row - 1, xx = x0 + col - 1;
        bf16x8 v = (bf16x8){0, 0, 0, 0, 0, 0, 0, 0};
        if (kc * 8 < ICS && (unsigned)yy < (unsigned)H_ && (unsigned)xx < (unsigned)W_) {
            v = ld_frag(&in[((size_t)b * HW_ + yy * W_ + xx) * ICS + kc * 8]);
        }
        *reinterpret_cast<bf16x8*>(&patch[(row * 18 + col) * COLP + kc * 8]) = v;
    }
    __syncthreads();

    int wave = t >> 6, lane = t & 63;
    int fr = lane & 15, fq = lane >> 4;
    int oct  = wave / WPO;
    int widx = wave - oct * WPO;
    int mt0  = widx * MTP;

    f32x4 acc[MTP][NACC];
    #pragma unroll
    for (int i = 0; i < MTP; ++i)
        #pragma unroll
        for (int a = 0; a < NACC; ++a)
            acc[i][a] = (f32x4){0.f, 0.f, 0.f, 0.f};

    constexpr int dyv[9] = {0,0,0,1,1,1,2,2,2};
    constexpr int dxv[9] = {0,1,2,0,1,2,0,1,2};

    #pragma unroll
    for (int tap = 0; tap < 9; ++tap) {
        int dy = dyv[tap], dx = dxv[tap];
        #pragma unroll
        for (int ks = 0; ks < NKS; ++ks) {
            const size_t wo = ((size_t)tap * COUT_PAD + oct * 16 + fr) * ICP + ks * 32 + fq * 8;
            bf16x8 wfA = ld_frag(&Wt[wo]);
            bf16x8 wfB;
            if (DUAL) wfB = ld_frag(&Wt2[wo]);
            #pragma unroll
            for (int i = 0; i < MTP; ++i) {
                bf16x8 pf = ld_frag(&patch[((mt0 + i + dy) * 18 + (fr + dx)) * COLP
                                           + ks * 32 + fq * 8]);
                acc[i][0] = __builtin_amdgcn_mfma_f32_16x16x32_bf16(wfA, pf, acc[i][0], 0, 0, 0);
                if (DUAL)
                    acc[i][1] = __builtin_amdgcn_mfma_f32_16x16x32_bf16(wfB, pf, acc[i][1], 0, 0, 0);
            }
        }
    }

    #pragma unroll
    for (int i = 0; i < MTP; ++i) {
        int py = mt0 + i;
        if (OMODE == 1) {
            size_t p = (size_t)b * HW_ + (size_t)(y0 + py) * W_ + x0 + fr;
            ushort4 sv;
            #pragma unroll
            for (int j = 0; j < 4; ++j) {
                float v = acc[i][0][j] + bias[oct * 16 + fq * 4 + j];
                if (RELU) v = fmaxf(v, 0.f);
                ((unsigned short*)&sv)[j] = f2bf(v);
            }
            *reinterpret_cast<ushort4*>(&outB[p * COUT_REAL + oct * 16 + fq * 4]) = sv;
        } else {
            #pragma unroll
            for (int j = 0; j < 4; ++j) {
                int oc = oct * 16 + fq * 4 + j;
                if (oc >= COUT_REAL) continue;
                size_t off = ((size_t)b * COUT_REAL + oc) * HW_
                           + (size_t)(y0 + py) * W_ + x0 + fr;
                float v = acc[i][0][j] + bias[oc];
                if (DUAL) {
                    float be = acc[i][1][j] + bias2[oc];
                    float nv = nrm[off];
                    outF[off] = fmaf(nv, 1.f + v, be);
                } else {
                    outF[off] = RELU ? fmaxf(v, 0.f) : v;
                }
            }
        }
    }
}

// ---------------------------------------------------------------------------
// DCNv2 fused + conv_off in-block. Block = 32 px (one row-third), 256 thr.
// phaseA: stage cond patch [3][34][72] bf16 (aliased over sS)
// phaseB: om MFMA (wtoff), write omL[32][36] f32 (+b_off)
// phase0: corner weights (f16-packed) / indices from omL
// phase1: f16 packed gather from ccH -> sS (f16)
// phase2: f16 MFMA matvec -> rrT bf16 [p][64]
// ---------------------------------------------------------------------------
constexpr int SROW = 584;
constexpr int DT   = 32;

__global__ __launch_bounds__(256)
void dcn_kernel(const unsigned short* __restrict__ ccH,
                const unsigned short* __restrict__ condT,
                const unsigned short* __restrict__ wtoff,
                const float* __restrict__ b_off,
                const unsigned short* __restrict__ wbdH,
                const float* __restrict__ b_dcn,
                unsigned short* __restrict__ rrT) {
    __shared__ unsigned short uS[DT * SROW];   // sS; start aliased as cond patch
    __shared__ float  omL[DT][36];
    __shared__ ushort4 cwLh[DT * 9];
    __shared__ int4    ciL[DT * 9];

    int t = threadIdx.x;
    // bijective XCD swizzle: nwg = 576, q = 72
    int bid = blockIdx.x;
    int swz = (bid & 7) * 72 + (bid >> 3);
    int b   = swz / (HW_ / DT);
    int p0  = (swz % (HW_ / DT)) * DT;
    int y   = p0 / W_, x0 = p0 - y * W_;

    // ---- phase A: stage cond patch rows y-1..y+1, cols x0-1..x0+32 ----
    for (int e = t; e < 3 * 34 * 8; e += 256) {
        int kc  = e & 7;
        int col = (e >> 3) % 34;
        int row = (e >> 3) / 34;
        int yy = y + row - 1, xx = x0 + col - 1;
        bf16x8 v = (bf16x8){0, 0, 0, 0, 0, 0, 0, 0};
        if ((unsigned)yy < (unsigned)H_ && (unsigned)xx < (unsigned)W_) {
            v = ld_frag(&condT[((size_t)b * HW_ + yy * W_ + xx) * 64 + kc * 8]);
        }
        *reinterpret_cast<bf16x8*>(&uS[(row * 34 + col) * 72 + kc * 8]) = v;
    }
    __syncthreads();

    int wave = t >> 6, lane = t & 63;
    int fr = lane & 15, fq = lane >> 4;

    // ---- phase B: om MFMA. wave w: oct = w&1, mt = w>>1 ----
    {
        int oct = wave & 1, mt = wave >> 1;
        f32x4 acc = (f32x4){0.f, 0.f, 0.f, 0.f};
        constexpr int dyv[9] = {0,0,0,1,1,1,2,2,2};
        constexpr int dxv[9] = {0,1,2,0,1,2,0,1,2};
        #pragma unroll
        for (int tap = 0; tap < 9; ++tap) {
            int dy = dyv[tap], dx = dxv[tap];
            #pragma unroll
            for (int ks = 0; ks < 2; ++ks) {
                bf16x8 wf = ld_frag(&wtoff[((size_t)tap * 32 + oct * 16 + fr) * 64
                                           + ks * 32 + fq * 8]);
                bf16x8 pf = *reinterpret_cast<const bf16x8*>(
                    &uS[(dy * 34 + mt * 16 + fr + dx) * 72 + ks * 32 + fq * 8]);
                acc = __builtin_amdgcn_mfma_f32_16x16x32_bf16(wf, pf, acc, 0, 0, 0);
            }
        }
        int px = mt * 16 + fr;
        float4 o4;
        #pragma unroll
        for (int j = 0; j < 4; ++j) {
            int oc = oct * 16 + fq * 4 + j;
            ((float*)&o4)[j] = acc[j] + (oc < 27 ? b_off[oc] : 0.f);
        }
        *reinterpret_cast<float4*>(&omL[px][oct * 16 + fq * 4]) = o4;
    }
    __syncthreads();

    // ---- phase 0: corner weights/indices from omL ----
    for (int e = t; e < DT * 9; e += 256) {
        int pp = e / 9, k = e - pp * 9;
        int p  = p0 + pp;
        int yq = p / W_, xq = p - yq * W_;
        float dy = omL[pp][2 * k];
        float dx = omL[pp][2 * k + 1];
        float mk = omL[pp][18 + k];
        mk = 1.f / (1.f + expf(-mk));

        float py = dy + (float)yq + (float)(k / 3 - 1);
        float px = dx + (float)xq + (float)(k % 3 - 1);
        float fy = floorf(py), fx = floorf(px);
        int   y0 = (int)fy,   x0c = (int)fx;
        float wy = py - fy,   wx = px - fx;

        ushort4 cwh;
        int   ci[4];
        #pragma unroll
        for (int i = 0; i < 4; ++i) {
            int yy = y0 + (i >> 1);
            int xx = x0c + (i & 1);
            bool valid = (yy >= 0) && (yy < H_) && (xx >= 0) && (xx < W_);
            int yc = yy < 0 ? 0 : (yy > H_ - 1 ? H_ - 1 : yy);
            int xc = xx < 0 ? 0 : (xx > W_ - 1 ? W_ - 1 : xx);
            ci[i] = yc * W_ + xc;
            float wyi = (i >> 1) ? wy : (1.f - wy);
            float wxi = (i & 1)  ? wx : (1.f - wx);
            ((unsigned short*)&cwh)[i] = f2hbits(valid ? mk * wyi * wxi : 0.f);
        }
        cwLh[e] = cwh;
        ciL[e] = make_int4(ci[0], ci[1], ci[2], ci[3]);
    }
    __syncthreads();

    // ---- phase 1: f16 packed gather ----
    {
        const unsigned short* ch = ccH + (size_t)b * HW_ * 64;
        int pp = t >> 3, cg8 = t & 7;
        #pragma unroll
        for (int k = 0; k < 9; ++k) {
            ushort4 cwh = cwLh[pp * 9 + k];
            int4    ci  = ciL[pp * 9 + k];
            f16x8 r0 = *reinterpret_cast<const f16x8*>(&ch[(size_t)ci.x * 64 + cg8 * 8]);
            f16x8 r1 = *reinterpret_cast<const f16x8*>(&ch[(size_t)ci.y * 64 + cg8 * 8]);
            f16x8 r2 = *reinterpret_cast<const f16x8*>(&ch[(size_t)ci.z * 64 + cg8 * 8]);
            f16x8 r3 = *reinterpret_cast<const f16x8*>(&ch[(size_t)ci.w * 64 + cg8 * 8]);
            _Float16 h0 = hfrombits(cwh.x);
            _Float16 h1 = hfrombits(cwh.y);
            _Float16 h2 = hfrombits(cwh.z);
            _Float16 h3 = hfrombits(cwh.w);
            f16x8 s = r0 * h0;
            s += r1 * h1;
            s += r2 * h2;
            s += r3 * h3;
            *reinterpret_cast<f16x8*>(&uS[pp * SROW + k * 64 + cg8 * 8]) = s;
        }
    }
    __syncthreads();

    // ---- phase 2: f16 MFMA matvec, 2 m-tiles per wave ----
    f32x4 acc0 = (f32x4){0.f, 0.f, 0.f, 0.f};
    f32x4 acc1 = (f32x4){0.f, 0.f, 0.f, 0.f};
    for (int ks = 0; ks < 18; ++ks) {
        f16x8 wf  = *reinterpret_cast<const f16x8*>(
            &wbdH[(size_t)(wave * 16 + fr) * 576 + ks * 32 + fq * 8]);
        f16x8 pf0 = *reinterpret_cast<const f16x8*>(
            &uS[(size_t)fr * SROW + ks * 32 + fq * 8]);
        f16x8 pf1 = *reinterpret_cast<const f16x8*>(
            &uS[(size_t)(16 + fr) * SROW + ks * 32 + fq * 8]);
        acc0 = __builtin_amdgcn_mfma_f32_16x16x32_f16(wf, pf0, acc0, 0, 0, 0);
        acc1 = __builtin_amdgcn_mfma_f32_16x16x32_f16(wf, pf1, acc1, 0, 0, 0);
    }

    {
        size_t p = (size_t)b * HW_ + p0 + fr;
        ushort4 sv0, sv1;
        #pragma unroll
        for (int j = 0; j < 4; ++j) {
            float bo = b_dcn[wave * 16 + fq * 4 + j];
            ((unsigned short*)&sv0)[j] = f2bf(acc0[j] + bo);
            ((unsigned short*)&sv1)[j] = f2bf(acc1[j] + bo);
        }
        *reinterpret_cast<ushort4*>(&rrT[p * 64 + wave * 16 + fq * 4]) = sv0;
        *reinterpret_cast<ushort4*>(&rrT[(p + 16) * 64 + wave * 16 + fq * 4]) = sv1;
    }
}

} // namespace

// ---------------------------------------------------------------------------
extern "C" void kernel_launch(void* const* d_in, const int* in_sizes, int n_in,
                              void* d_out, int out_size, void* d_ws, size_t ws_size,
                              hipStream_t stream) {
    (void)in_sizes; (void)n_in; (void)out_size; (void)ws_size;

    const float* x     = (const float*)d_in[0];
    const float* ref   = (const float*)d_in[1];
    const float* w1    = (const float*)d_in[2];
    const float* b1    = (const float*)d_in[3];
    const float* w2    = (const float*)d_in[4];
    const float* b2    = (const float*)d_in[5];
    const float* w_off = (const float*)d_in[6];
    const float* b_off = (const float*)d_in[7];
    const float* w_dcn = (const float*)d_in[8];
    const float* b_dcn = (const float*)d_in[9];
    const float* w_g   = (const float*)d_in[10];
    const float* b_g   = (const float*)d_in[11];
    const float* w_be  = (const float*)d_in[12];
    const float* b_be  = (const float*)d_in[13];

    float* out = (float*)d_out;
    float* ws  = (float*)d_ws;

    float* nrm = ws;                                          // [b][c][p] f32
    unsigned short* cc    = (unsigned short*)(nrm + 1179648); // [b][p][128] bf16
    unsigned short* ccH   = cc    + 2359296;                  // [b][p][64]  f16
    unsigned short* hmidT = ccH   + 1179648;                  // [b][p][16]  bf16
    unsigned short* condT = hmidT + 294912;                   // [b][p][64]  bf16
    unsigned short* rrT   = condT + 1179648;                  // [b][p][64]  bf16
    unsigned short* wt1   = rrT   + 1179648;
    unsigned short* wt2   = wt1   + 18432;
    unsigned short* wtoff = wt2   + 18432;
    unsigned short* wtg   = wtoff + 18432;
    unsigned short* wtbe  = wtg   + 36864;
    unsigned short* wbdH  = wtbe  + 36864;

    prologue<<<432, 256, 0, stream>>>(x, ref, w1, w2, w_off, w_g, w_be, w_dcn,
                                      nrm, cc, ccH, wt1, wt2, wtoff, wtg, wtbe, wbdH);

    constexpr int GRID = 288;

    conv_bf<128, 128, 136, 16, 16, false, true, 1>
        <<<GRID, 256, 0, stream>>>(cc, wt1, nullptr, b1, nullptr, nullptr, nullptr, hmidT);

    conv_bf<16, 32, 40, 64, 64, false, true, 1>
        <<<GRID, 256, 0, stream>>>(hmidT, wt2, nullptr, b2, nullptr, nullptr, nullptr, condT);

    dcn_kernel<<<B_ * (HW_ / DT), 256, 0, stream>>>(ccH, condT, wtoff, b_off,
                                                    wbdH, b_dcn, rrT);

    conv_bf<64, 64, 72, 64, 64, true, false, 0>
        <<<GRID, 256, 0, stream>>>(rrT, wtg, wtbe, b_g, b_be, nrm, out, nullptr);
}